// Round 7
// baseline (316.617 us; speedup 1.0000x reference)
//
#include <hip/hip_runtime.h>
#include <float.h>
#include <math.h>

// Problem constants
#define B_SZ 1024
#define D_SZ 8192
#define C_SZ 345
#define F_SZ 512
#define PROTO_W 0.99f

// d_out layout (float32, flat, reference return order):
//   logits   [2048][345]  @ 0
//   new_proto[345][512]   @ 706560
//   scores   [345][345]   @ 883200
//   labels   [1024]       @ 1002225  (stored as float)
//   feats    [2048][512]  @ 1003249

// ---------------- NEW-path d_ws layout -----------
// R14: Xh/Xl hold packed A tiles [mt 0..15][kstep32 0..255][4096 shorts];
// Wh/Wl packed B tiles [nt 0..3][kstep32 0..255][4096 shorts].
#define WS_XH 0
#define WS_XL 33554432u
#define WS_WH 67108864u
#define WS_WL 75497472u
#define WS_P  83886080u
#define WS2_WFH 100663296u
#define WS2_WFL 101056512u
#define WS2_LAB 101449728u
#define WS2_NEED 101457920u

// ---------------- OLD-path (R6 fallback) overlay offsets ---------------------
#define WS_NEED 92274688u
#define WS_FH  0u
#define WS_FL  2097152u
#define WS_WFH 4194304u
#define WS_WFL 4587520u
#define WS_NPH 4980736u
#define WS_NPL 5373952u

typedef short bf16x8 __attribute__((ext_vector_type(8)));
typedef short short4v __attribute__((ext_vector_type(4)));
typedef short short8v __attribute__((ext_vector_type(8)));
typedef float f32x4  __attribute__((ext_vector_type(4)));

__device__ __forceinline__ void split_bf16(float x, short& hi, short& lo) {
    unsigned u = __float_as_uint(x);
    unsigned r = (u + 0x7FFFu + ((u >> 16) & 1u)) >> 16;
    hi = (short)r;
    float hf = __uint_as_float(r << 16);
    lo = (short)(__float_as_uint(x - hf) >> 16);
}
__device__ __forceinline__ float bf16_f32(short h) {
    return __uint_as_float(((unsigned)(unsigned short)h) << 16);
}

__device__ __forceinline__ void gl_lds16(const short* g, short* l) {
    __builtin_amdgcn_global_load_lds(
        (const __attribute__((address_space(1))) void*)g,
        (__attribute__((address_space(3))) void*)l, 16, 0, 0);
}

// order-preserving float -> u32 key (larger float => larger key)
__device__ __forceinline__ unsigned f2key(float v) {
    unsigned u = __float_as_uint(v);
    return (u & 0x80000000u) ? ~u : (u | 0x80000000u);
}

// Raw barrier with compiler memory fence but NO hardware counter drain.
__device__ __forceinline__ void fence_barrier() {
    asm volatile("" ::: "memory");
    __builtin_amdgcn_s_barrier();
    asm volatile("" ::: "memory");
}

#define MFMA_BF16 __builtin_amdgcn_mfma_f32_16x16x32_bf16

// 12-MFMA bf16x3 block (2x2 frags); expects sAh/sAl/sBh/sBl + acc in scope.
#define MFMA_BLOCK(IA0, IA1, IB0, IB1)                                   \
    do {                                                                 \
        bf16x8 a0h = *(const bf16x8*)&sAh[IA0];                          \
        bf16x8 a1h = *(const bf16x8*)&sAh[IA1];                          \
        bf16x8 b0h = *(const bf16x8*)&sBh[IB0];                          \
        bf16x8 b1h = *(const bf16x8*)&sBh[IB1];                          \
        bf16x8 a0l = *(const bf16x8*)&sAl[IA0];                          \
        bf16x8 a1l = *(const bf16x8*)&sAl[IA1];                          \
        bf16x8 b0l = *(const bf16x8*)&sBl[IB0];                          \
        bf16x8 b1l = *(const bf16x8*)&sBl[IB1];                          \
        acc[0][0] = MFMA_BF16(a0h, b0h, acc[0][0], 0, 0, 0);             \
        acc[0][1] = MFMA_BF16(a0h, b1h, acc[0][1], 0, 0, 0);             \
        acc[1][0] = MFMA_BF16(a1h, b0h, acc[1][0], 0, 0, 0);             \
        acc[1][1] = MFMA_BF16(a1h, b1h, acc[1][1], 0, 0, 0);             \
        acc[0][0] = MFMA_BF16(a0h, b0l, acc[0][0], 0, 0, 0);             \
        acc[0][1] = MFMA_BF16(a0h, b1l, acc[0][1], 0, 0, 0);             \
        acc[1][0] = MFMA_BF16(a1h, b0l, acc[1][0], 0, 0, 0);             \
        acc[1][1] = MFMA_BF16(a1h, b1l, acc[1][1], 0, 0, 0);             \
        acc[0][0] = MFMA_BF16(a0l, b0h, acc[0][0], 0, 0, 0);             \
        acc[0][1] = MFMA_BF16(a0l, b1h, acc[0][1], 0, 0, 0);             \
        acc[1][0] = MFMA_BF16(a1l, b0h, acc[1][0], 0, 0, 0);             \
        acc[1][1] = MFMA_BF16(a1l, b1h, acc[1][1], 0, 0, 0);             \
    } while (0)

// ---------------------------------------------------------------------------
// R14 packed layout: per (128-row-group, 32-k) tile = 4096 shorts.
// Element (pr 0..127, k 0..31): half = pr>>6, r = pr&63, rp = r>>1, p = r&1,
// c = k>>3, slot = ((p<<2)|c) ^ (rp&7):
//   off = half*2048 + rp*64 + slot*8 + (k&7)
// ---------------------------------------------------------------------------

// ---------------------------------------------------------------------------
// convert_pack2: X -> packed A tiles; W_enc -> packed B tiles;
// W_fc -> Wth/Wtl (unchanged layout); zeroes labPack (incl. the 64 tile
// counters the gemm uses in labPack[0..63]). grid 2096 x 256.
// ---------------------------------------------------------------------------
__global__ __launch_bounds__(256) void convert_pack2(
    const float* __restrict__ img_q, const float* __restrict__ img_q1,
    const float* __restrict__ W_enc, const float* __restrict__ W_fc,
    short* __restrict__ Ahp, short* __restrict__ Alp,
    short* __restrict__ Bhp, short* __restrict__ Blp,
    short* __restrict__ Wth, short* __restrict__ Wtl,
    unsigned long long* __restrict__ labPack)
{
    __shared__ float tile[64][65];
    const int bid = blockIdx.x;
    const int t = threadIdx.x;

    if (bid < 4)
        labPack[bid * 256 + t] = 0ull;

    if (bid < 1024) {
        const int total = 2048 * 1024;
        for (int i = bid * 256 + t; i < total; i += 1024 * 256) {
            const int row = i >> 10;
            const int cc = i & 1023;
            const float* src = (row < B_SZ)
                ? &img_q[(size_t)row * D_SZ + cc * 8]
                : &img_q1[(size_t)(row - B_SZ) * D_SZ + cc * 8];
            float4 a = ((const float4*)src)[0];
            float4 b = ((const float4*)src)[1];
            float f[8] = {a.x, a.y, a.z, a.w, b.x, b.y, b.z, b.w};
            short8v h, l;
#pragma unroll
            for (int e = 0; e < 8; ++e) {
                short hh, ll;
                split_bf16(f[e], hh, ll);
                h[e] = hh; l[e] = ll;
            }
            const int mt = row >> 7;
            const int pr = row & 127;
            const int kstep = cc >> 2;
            const int c = cc & 3;
            const int hf = pr >> 6;
            const int r = pr & 63;
            const int rp = r >> 1;
            const int slot = (((r & 1) << 2) | c) ^ (rp & 7);
            const size_t dst = (size_t)(mt * 256 + kstep) * 4096
                             + hf * 2048 + rp * 64 + slot * 8;
            *(short8v*)&Ahp[dst] = h;
            *(short8v*)&Alp[dst] = l;
        }
    } else if (bid < 2048) {
        const int id = bid - 1024;
        const int kstep64 = id >> 3;
        const int k0 = kstep64 * 64;
        const int n0 = (id & 7) * 64;
        {
            const int kr = t >> 2;
            const int cb = (t & 3) * 16;
#pragma unroll
            for (int j = 0; j < 4; ++j) {
                float4 v = *(const float4*)&W_enc[(size_t)(k0 + kr) * F_SZ + n0 + cb + j * 4];
                tile[kr][cb + j * 4 + 0] = v.x;
                tile[kr][cb + j * 4 + 1] = v.y;
                tile[kr][cb + j * 4 + 2] = v.z;
                tile[kr][cb + j * 4 + 3] = v.w;
            }
        }
        __syncthreads();
        const int n = t >> 2;
#pragma unroll
        for (int cc2 = 0; cc2 < 2; ++cc2) {
            const int ch = (t & 3) * 2 + cc2;
            short8v h, l;
#pragma unroll
            for (int e = 0; e < 8; ++e) {
                short hh, ll;
                split_bf16(tile[ch * 8 + e][n], hh, ll);
                h[e] = hh; l[e] = ll;
            }
            const int nrow = n0 + n;
            const int k32 = kstep64 * 2 + (ch >> 2);
            const int c = ch & 3;
            const int nt_ = nrow >> 7;
            const int pr = nrow & 127;
            const int hf = pr >> 6;
            const int r = pr & 63;
            const int rp = r >> 1;
            const int slot = (((r & 1) << 2) | c) ^ (rp & 7);
            const size_t dst = (size_t)(nt_ * 256 + k32) * 4096
                             + hf * 2048 + rp * 64 + slot * 8;
            *(short8v*)&Bhp[dst] = h;
            *(short8v*)&Blp[dst] = l;
        }
    } else {
        const int id = bid - 2048;
        const int k0 = (id & 7) * 64;
        const int c0 = (id >> 3) * 64;
        for (int idx = t; idx < 64 * 64; idx += 256) {
            const int kr = idx >> 6;
            const int cc = idx & 63;
            tile[kr][cc] = (c0 + cc < C_SZ) ? W_fc[(size_t)(k0 + kr) * C_SZ + c0 + cc] : 0.0f;
        }
        __syncthreads();
        const int crow = t >> 2;
#pragma unroll
        for (int cc2 = 0; cc2 < 2; ++cc2) {
            const int ch = (t & 3) * 2 + cc2;
            short8v h, l;
#pragma unroll
            for (int e = 0; e < 8; ++e) {
                short hh, ll;
                split_bf16(tile[ch * 8 + e][crow], hh, ll);
                h[e] = hh; l[e] = ll;
            }
            size_t off = (size_t)(c0 + crow) * F_SZ + k0 + ch * 8;
            *(short8v*)&Wth[off] = h;
            *(short8v*)&Wtl[off] = l;
        }
    }
}

// ---------------------------------------------------------------------------
// gemm_ws128_v6 (R15): R14's deep pipeline (BK=32, 4 LDS bufs, depth-3
// prefetch, 1 barrier/step, vmcnt(8), setprio) + FUSED split-K reduction:
// after the P store, each block atomicAdds labPack[tile]; the 4th arrival
// re-reads all 4 slices in fixed slice order (bit-identical to the old
// reduce_feats4) and writes feats fp32. labPack[0..63] double as counters
// (residue 4 < any fc argmax key, which is >= 2^32 — fc atomicMax overrides).
// grid (4,16,4) x 512 threads.
// ---------------------------------------------------------------------------
#define V5_MFMA(PAH, PAL, PBH, PBL)                                          \
    do {                                                                     \
        bf16x8 ah[4], al[4], bh_[2], bl_[2];                                 \
        _Pragma("unroll")                                                    \
        for (int f = 0; f < 4; ++f) {                                        \
            ah[f] = *(const bf16x8*)&(PAH)[aoff[f]];                         \
            al[f] = *(const bf16x8*)&(PAL)[aoff[f]];                         \
        }                                                                    \
        _Pragma("unroll")                                                    \
        for (int g = 0; g < 2; ++g) {                                        \
            bh_[g] = *(const bf16x8*)&(PBH)[boff[g]];                        \
            bl_[g] = *(const bf16x8*)&(PBL)[boff[g]];                        \
        }                                                                    \
        __builtin_amdgcn_s_setprio(1);                                       \
        _Pragma("unroll")                                                    \
        for (int f = 0; f < 4; ++f)                                          \
            _Pragma("unroll")                                                \
            for (int g = 0; g < 2; ++g)                                      \
                acc[f][g] = MFMA_BF16(ah[f], bh_[g], acc[f][g], 0, 0, 0);    \
        _Pragma("unroll")                                                    \
        for (int f = 0; f < 4; ++f)                                          \
            _Pragma("unroll")                                                \
            for (int g = 0; g < 2; ++g)                                      \
                acc[f][g] = MFMA_BF16(ah[f], bl_[g], acc[f][g], 0, 0, 0);    \
        _Pragma("unroll")                                                    \
        for (int f = 0; f < 4; ++f)                                          \
            _Pragma("unroll")                                                \
            for (int g = 0; g < 2; ++g)                                      \
                acc[f][g] = MFMA_BF16(al[f], bh_[g], acc[f][g], 0, 0, 0);    \
        __builtin_amdgcn_s_setprio(0);                                       \
    } while (0)

#define V5_STEP(BI, SD, SW, VMLIT)                                           \
    do {                                                                     \
        asm volatile("s_waitcnt vmcnt(" VMLIT ")" ::: "memory");             \
        fence_barrier();                                                     \
        {                                                                    \
            const short* gg = gsrc0 + (size_t)(SW) * 4096;                   \
            gl_lds16(gg, SD);                                                \
            gl_lds16(gg + 512, (SD) + 512);                                  \
            gl_lds16(gg + 1024, (SD) + 1024);                                \
            gl_lds16(gg + 1536, (SD) + 1536);                                \
        }                                                                    \
        V5_MFMA(SAh[BI], SAl[BI], SBh[BI], SBl[BI]);                         \
    } while (0)

#define V5_STEPN(BI, VMLIT)                                                  \
    do {                                                                     \
        asm volatile("s_waitcnt vmcnt(" VMLIT ")" ::: "memory");             \
        fence_barrier();                                                     \
        V5_MFMA(SAh[BI], SAl[BI], SBh[BI], SBl[BI]);                         \
    } while (0)

__global__ __launch_bounds__(512, 1) void gemm_ws128_v6(
    const short* __restrict__ Ahp, const short* __restrict__ Alp,
    const short* __restrict__ Bhp, const short* __restrict__ Blp,
    float* __restrict__ P, float* __restrict__ feats,
    unsigned long long* __restrict__ tileCnt)
{
    __shared__ __align__(16) short SAh[4][4096];
    __shared__ __align__(16) short SAl[4][4096];
    __shared__ __align__(16) short SBh[4][4096];
    __shared__ __align__(16) short SBl[4][4096];

    const int t = threadIdx.x;
    const int lane = t & 63;
    const int wave = t >> 6;

    // XCD-aware bijective swizzle (flat id, nwg = 256)
    const int flat = blockIdx.x + 4 * blockIdx.y + 64 * blockIdx.z;
    const int logical = (flat & 7) * 32 + (flat >> 3);
    const int nt = logical & 3;
    const int mt = (logical >> 2) & 15;
    const int ks = logical >> 6;

    const int m0 = mt * 128;
    const int n0 = nt * 128;

    const int arr = wave >> 1;
    const int half = wave & 1;
    const short* gtile =
        (arr == 0) ? Ahp + (size_t)(mt * 256) * 4096 :
        (arr == 1) ? Alp + (size_t)(mt * 256) * 4096 :
        (arr == 2) ? Bhp + (size_t)(nt * 256) * 4096 :
                     Blp + (size_t)(nt * 256) * 4096;
    const short* gsrc0 = gtile + (size_t)(ks * 64) * 4096 + half * 2048 + lane * 8;

    short* abase =
        (arr == 0) ? &SAh[0][0] : (arr == 1) ? &SAl[0][0] :
        (arr == 2) ? &SBh[0][0] : &SBl[0][0];
    short* sd0 = abase + 0 * 4096 + half * 2048;
    short* sd1 = abase + 1 * 4096 + half * 2048;
    short* sd2 = abase + 2 * 4096 + half * 2048;
    short* sd3 = abase + 3 * 4096 + half * 2048;

    const int wr = wave >> 2;
    const int wc = wave & 3;
    const int mo = wr * 64;
    const int no = wc * 32;
    const int lr = lane & 15;
    const int lkg = lane >> 4;
    int aoff[4], boff[2];
#pragma unroll
    for (int f = 0; f < 4; ++f) {
        const int R = mo + 16 * f + lr;
        const int r = R & 63;
        const int rp = r >> 1;
        aoff[f] = (R >> 6) * 2048 + rp * 64
                + (((((r & 1) << 2) | lkg)) ^ (rp & 7)) * 8;
    }
#pragma unroll
    for (int g = 0; g < 2; ++g) {
        const int R = no + 16 * g + lr;
        const int r = R & 63;
        const int rp = r >> 1;
        boff[g] = (R >> 6) * 2048 + rp * 64
                + (((((r & 1) << 2) | lkg)) ^ (rp & 7)) * 8;
    }

    f32x4 acc[4][2] = {};

    // prologue: stage steps 0,1,2 into buffers 0,1,2 (12 loads in flight)
    {
        gl_lds16(gsrc0,        sd0);
        gl_lds16(gsrc0 + 512,  sd0 + 512);
        gl_lds16(gsrc0 + 1024, sd0 + 1024);
        gl_lds16(gsrc0 + 1536, sd0 + 1536);
        const short* g1 = gsrc0 + 4096;
        gl_lds16(g1,        sd1);
        gl_lds16(g1 + 512,  sd1 + 512);
        gl_lds16(g1 + 1024, sd1 + 1024);
        gl_lds16(g1 + 1536, sd1 + 1536);
        const short* g2 = gsrc0 + 8192;
        gl_lds16(g2,        sd2);
        gl_lds16(g2 + 512,  sd2 + 512);
        gl_lds16(g2 + 1024, sd2 + 1024);
        gl_lds16(g2 + 1536, sd2 + 1536);
    }

    // main: steps 0..59 (steady state: vmcnt(8), issue s+3 after barrier)
    for (int s4 = 0; s4 < 15; ++s4) {
        const int sb = s4 * 4;
        V5_STEP(0, sd3, sb + 3, "8");
        V5_STEP(1, sd0, sb + 4, "8");
        V5_STEP(2, sd1, sb + 5, "8");
        V5_STEP(3, sd2, sb + 6, "8");
    }
    // peeled tail: s = 60..63
    V5_STEP (0, sd3, 63, "8");
    V5_STEPN(1, "8");
    V5_STEPN(2, "4");
    V5_STEPN(3, "0");

    float* Pout = P + (size_t)ks * (2048u * 512u);
#pragma unroll
    for (int f = 0; f < 4; ++f)
#pragma unroll
        for (int g = 0; g < 2; ++g) {
            const int col  = n0 + no + 16 * g + (lane & 15);
            const int row0 = m0 + mo + 16 * f + (lane >> 4) * 4;
#pragma unroll
            for (int r = 0; r < 4; ++r)
                Pout[(size_t)(row0 + r) * F_SZ + col] = acc[f][g][r];
        }

    // ---- fused split-K reduction (R15): last block of the 4 ks-siblings ---
    asm volatile("s_waitcnt vmcnt(0)" ::: "memory");
    __threadfence();
    __syncthreads();
    if (t == 0) {
        unsigned long long old = atomicAdd(&tileCnt[mt * 4 + nt], 1ull);
        *(int*)&SAh[0][0] = (old == 3ull) ? 1 : 0;
    }
    __syncthreads();
    if (*(int*)&SAh[0][0]) {
        __threadfence();   // acquire: other slices' stores now visible
#pragma unroll
        for (int q = 0; q < 8; ++q) {
            const int idx = t + q * 512;
            const int row = idx >> 5;
            const int ch = idx & 31;
            const size_t g = (size_t)(m0 + row) * F_SZ + n0 + ch * 4;
            float4 v = *(const float4*)&P[g];
#pragma unroll
            for (int sl = 1; sl < 4; ++sl) {
                float4 b = *(const float4*)&P[(size_t)sl * (2048u * 512u) + g];
                v.x += b.x; v.y += b.y; v.z += b.z; v.w += b.w;
            }
            *(float4*)&feats[g] = v;
        }
    }
}

// ---------------------------------------------------------------------------
// fc_logits4 (R15): logits = feats @ W_fc^T + bias, A staged from fp32 feats
// (reg-load -> split_bf16 -> ds_write into the SAME swizzled LDS slots the
// old gl_lds path produced -> bit-identical MFMA inputs). Waves 0/1 stage A
// (T14 issue-early/write-late across the double buffer), waves 2/3 keep the
// proven gl_lds B path. Fused packed-atomicMax masked argmax. grid (6,32).
// ---------------------------------------------------------------------------
__global__ __launch_bounds__(256, 2) void fc_logits4(
    const float* __restrict__ feats,
    const short* __restrict__ Bh_g, const short* __restrict__ Bl_g,
    const float* __restrict__ bias, const float* __restrict__ partial_Y,
    float* __restrict__ logits, unsigned long long* __restrict__ labPack)
{
    __shared__ __align__(16) short dAh[2][4096];
    __shared__ __align__(16) short dAl[2][4096];
    __shared__ __align__(16) short dBh[2][4096];
    __shared__ __align__(16) short dBl[2][4096];

    const int t = threadIdx.x;
    const int lane = t & 63;
    const int wave = t >> 6;
    const int n0 = blockIdx.x * 64;
    const int m0 = blockIdx.y * 64;

    const int lrow8 = lane >> 3;
    const int cg = (lane & 7) ^ lrow8;     // col group 0..7 (swizzled source)
    const bool isA = (wave < 2);

    // B staging (waves 2/3): unchanged gl_lds path
    const short* gB = (wave == 2) ? Bh_g : Bl_g;
    short* lbB[2];
    lbB[0] = (wave == 2) ? dBh[0] : dBl[0];
    lbB[1] = (wave == 2) ? dBh[1] : dBl[1];
    const short* gbaseB = gB + (size_t)(n0 + lrow8) * F_SZ + cg * 8;

    // A staging (waves 0/1): j = wave*4 + j2, row = m0 + lrow8 + 8*j,
    // src feats[row][s*64 + cg*8 .. +8] fp32 -> dAh/dAl[buf][j*512 + lane*8]
    const float* gA0 = feats + (size_t)(m0 + lrow8 + 8 * (wave * 4)) * F_SZ + cg * 8;

    // compute role (identical to fc_logits3)
    const int mo = (wave >> 1) * 32;
    const int no = (wave & 1) * 32;
    const int lr = lane & 15;
    const int lkg = lane >> 4;
    const int x7 = lr & 7;
    const int sl0 = (0 + lkg) ^ x7;
    const int sl1 = (4 + lkg) ^ x7;
    const int ra0 = (mo + lr) * 64,      ra1 = (mo + 16 + lr) * 64;
    const int rb0 = (no + lr) * 64,      rb1 = (no + 16 + lr) * 64;
    const int a00 = ra0 + sl0 * 8, a01 = ra0 + sl1 * 8;
    const int a10 = ra1 + sl0 * 8, a11 = ra1 + sl1 * 8;
    const int b00 = rb0 + sl0 * 8, b01 = rb0 + sl1 * 8;
    const int b10 = rb1 + sl0 * 8, b11 = rb1 + sl1 * 8;

    f32x4 acc[2][2] = {};

    // prologue: stage buf0 (s = 0)
    if (isA) {
#pragma unroll
        for (int j2 = 0; j2 < 4; ++j2) {
            const float* src = gA0 + (size_t)(8 * j2) * F_SZ;
            float4 v0 = ((const float4*)src)[0];
            float4 v1 = ((const float4*)src)[1];
            float f8[8] = {v0.x, v0.y, v0.z, v0.w, v1.x, v1.y, v1.z, v1.w};
            bf16x8 h, l;
#pragma unroll
            for (int e = 0; e < 8; ++e) {
                short hh, ll;
                split_bf16(f8[e], hh, ll);
                h[e] = hh; l[e] = ll;
            }
            const int j = wave * 4 + j2;
            *(bf16x8*)&dAh[0][j * 512 + lane * 8] = h;
            *(bf16x8*)&dAl[0][j * 512 + lane * 8] = l;
        }
        asm volatile("s_waitcnt lgkmcnt(0)" ::: "memory");
    } else {
#pragma unroll
        for (int j = 0; j < 8; ++j)
            gl_lds16(gbaseB + (size_t)(8 * j) * F_SZ, lbB[0] + j * 512);
    }

    int buf = 0;
    for (int s = 0; s < 8; ++s) {
        float4 ra[4][2];
        if (isA) {
            if (s + 1 < 8) {
                // issue-early: fp32 loads for step s+1 (arrive under MFMA)
#pragma unroll
                for (int j2 = 0; j2 < 4; ++j2) {
                    const float* src = gA0 + (size_t)(8 * j2) * F_SZ + (s + 1) * 64;
                    ra[j2][0] = ((const float4*)src)[0];
                    ra[j2][1] = ((const float4*)src)[1];
                }
            }
        } else {
            if (s + 1 < 8) {
                short* dst = lbB[buf ^ 1];
                const short* g = gbaseB + (s + 1) * 64;
#pragma unroll
                for (int j = 0; j < 8; ++j)
                    gl_lds16(g + (size_t)(8 * j) * F_SZ, dst + j * 512);
                asm volatile("s_waitcnt vmcnt(8)" ::: "memory");
            } else {
                asm volatile("s_waitcnt vmcnt(0)" ::: "memory");
            }
        }
        fence_barrier();   // buf (step s) fully staged for all waves
        __builtin_amdgcn_s_setprio(1);
        {
            const short* sAh = dAh[buf];
            const short* sAl = dAl[buf];
            const short* sBh = dBh[buf];
            const short* sBl = dBl[buf];
            MFMA_BLOCK(a00, a10, b00, b10);
            MFMA_BLOCK(a01, a11, b01, b11);
        }
        __builtin_amdgcn_s_setprio(0);
        if (isA && s + 1 < 8) {
            // write-late: regs -> split -> ds_write into buf^1
            asm volatile("s_waitcnt vmcnt(0)" ::: "memory");
#pragma unroll
            for (int j2 = 0; j2 < 4; ++j2) {
                float f8[8] = {ra[j2][0].x, ra[j2][0].y, ra[j2][0].z, ra[j2][0].w,
                               ra[j2][1].x, ra[j2][1].y, ra[j2][1].z, ra[j2][1].w};
                bf16x8 h, l;
#pragma unroll
                for (int e = 0; e < 8; ++e) {
                    short hh, ll;
                    split_bf16(f8[e], hh, ll);
                    h[e] = hh; l[e] = ll;
                }
                const int j = wave * 4 + j2;
                *(bf16x8*)&dAh[buf ^ 1][j * 512 + lane * 8] = h;
                *(bf16x8*)&dAl[buf ^ 1][j * 512 + lane * 8] = l;
            }
            asm volatile("s_waitcnt lgkmcnt(0)" ::: "memory");
        }
        fence_barrier();   // readers of buf done; A-writes to buf^1 drained
        buf ^= 1;
    }

    const bool doArg = (m0 < B_SZ);
#pragma unroll
    for (int f = 0; f < 2; ++f) {
#pragma unroll
        for (int r = 0; r < 4; ++r) {
            const int row = m0 + mo + f * 16 + (lane >> 4) * 4 + r;
            unsigned long long best = 0;
#pragma unroll
            for (int g = 0; g < 2; ++g) {
                const int col = n0 + no + g * 16 + (lane & 15);
                if (col < C_SZ) {
                    const float v = acc[f][g][r] + bias[col];
                    logits[(size_t)row * C_SZ + col] = v;
                    if (doArg && partial_Y[(size_t)row * C_SZ + col] != 0.0f) {
                        unsigned long long p = ((unsigned long long)f2key(v) << 32)
                                             | (unsigned long long)(0xFFFFFFFFu - (unsigned)col);
                        if (p > best) best = p;
                    }
                }
            }
            if (doArg) {
#pragma unroll
                for (int m = 1; m < 16; m <<= 1) {
                    unsigned long long o = __shfl_xor(best, m);
                    if (o > best) best = o;
                }
                if ((lane & 15) == 0 && best != 0)
                    atomicMax(&labPack[row], best);
            }
        }
    }
}

// ---------------------------------------------------------------------------
// proto_scores_fused: per class c — ballot-decode labPack, ordered EMA,
// L2 renorm, coalesced scores row. grid 345, 512 threads.
// ---------------------------------------------------------------------------
__global__ __launch_bounds__(512) void proto_scores_fused(
    const unsigned long long* __restrict__ labPack,
    const float* __restrict__ feats_q,
    const float* __restrict__ proto,
    const short* __restrict__ Wth, const short* __restrict__ Wtl,
    const float* __restrict__ b_fc,
    float* __restrict__ new_proto, float* __restrict__ scores,
    float* __restrict__ labels_f)
{
    __shared__ int rowlist[B_SZ];
    __shared__ int mcount_s;
    __shared__ float nprow[F_SZ];
    __shared__ float red[8];
    __shared__ float rinv_s;
    const int c = blockIdx.x;
    const int t = threadIdx.x;
    const int lane = t & 63;
    const int w = t >> 6;

    if (c == 0) {
#pragma unroll
        for (int j = 0; j < 2; ++j) {
            const int i = t + j * 512;
            int li = (int)(0xFFFFFFFFu - (unsigned)(labPack[i] & 0xFFFFFFFFull));
            labels_f[i] = (float)li;
        }
    }

    if (w == 0) {
        int k = 0;
#pragma unroll
        for (int ch = 0; ch < 16; ++ch) {
            unsigned long long pk = labPack[ch * 64 + lane];
            int li = (int)(0xFFFFFFFFu - (unsigned)(pk & 0xFFFFFFFFull));
            unsigned long long mask = __ballot(li == c);
            if (lane == 0) {
                while (mask) {
                    int p = __builtin_ctzll(mask);
                    mask &= mask - 1;
                    rowlist[k++] = ch * 64 + p;
                }
            }
            k = __shfl(k, 0);
        }
        if (lane == 0) mcount_s = k;
    }
    __syncthreads();
    const int m = mcount_s;

    float val = proto[(size_t)c * F_SZ + t];
    for (int k = 0; k < m; ++k)
        val = PROTO_W * val + (1.0f - PROTO_W) * feats_q[(size_t)rowlist[k] * F_SZ + t];

    float sq = val * val;
#pragma unroll
    for (int off = 32; off; off >>= 1) sq += __shfl_down(sq, off);
    if ((t & 63) == 0) red[t >> 6] = sq;
    __syncthreads();
    if (t == 0) {
        float s = 0.0f;
#pragma unroll
        for (int ww = 0; ww < 8; ++ww) s += red[ww];
        rinv_s = 1.0f / sqrtf(s);
    }
    __syncthreads();
    const float v = val * rinv_s;
    new_proto[(size_t)c * F_SZ + t] = v;
    nprow[t] = v;
    __syncthreads();

    float np8[8];
#pragma unroll
    for (int j = 0; j < 8; ++j) np8[j] = nprow[lane * 8 + j];
    for (int col = w; col < C_SZ; col += 8) {
        const short8v h = *(const short8v*)&Wth[(size_t)col * F_SZ + lane * 8];
        const short8v l = *(const short8v*)&Wtl[(size_t)col * F_SZ + lane * 8];
        float p = 0.0f;
#pragma unroll
        for (int j = 0; j < 8; ++j)
            p += np8[j] * (bf16_f32(h[j]) + bf16_f32(l[j]));
#pragma unroll
        for (int off = 32; off; off >>= 1) p += __shfl_down(p, off);
        if (lane == 0) scores[(size_t)c * C_SZ + col] = p + b_fc[col];
    }
}

// ===========================================================================
// OLD-path kernels (R6-proven fallback; used when ws < WS2_NEED)
// ===========================================================================
__global__ __launch_bounds__(256) void convert_all(
    const float* __restrict__ img_q, const float* __restrict__ img_q1,
    const float* __restrict__ W_enc, const float* __restrict__ W_fc,
    short* __restrict__ Xh, short* __restrict__ Xl,
    short* __restrict__ Wh, short* __restrict__ Wl,
    short* __restrict__ Wth, short* __restrict__ Wtl,
    unsigned long long* __restrict__ labPack)
{
    __shared__ float tile[64][65];
    const int bid = blockIdx.x;
    const int t = threadIdx.x;

    if (labPack && bid < 4)
        labPack[bid * 256 + t] = 0ull;

    if (bid < 1024) {
        const int HALF = (B_SZ * D_SZ) / 4;
        const int total = 2 * HALF;
        for (int i4 = bid * 256 + t; i4 < total; i4 += 1024 * 256) {
            float4 v = (i4 < HALF) ? ((const float4*)img_q)[i4]
                                   : ((const float4*)img_q1)[i4 - HALF];
            short4v h, l;
            short hh, ll;
            split_bf16(v.x, hh, ll); h.x = hh; l.x = ll;
            split_bf16(v.y, hh, ll); h.y = hh; l.y = ll;
            split_bf16(v.z, hh, ll); h.z = hh; l.z = ll;
            split_bf16(v.w, hh, ll); h.w = hh; l.w = ll;
            ((short4v*)Xh)[i4] = h;
            ((short4v*)Xl)[i4] = l;
        }
    } else if (bid < 2048) {
        const int id = bid - 1024;
        const int k0 = (id >> 3) * 64;
        const int n0 = (id & 7) * 64;
        {
            const int kr = t >> 2;
            const int cb = (t & 3) * 16;
#pragma unroll
            for (int j = 0; j < 4; ++j) {
                float4 v = *(const float4*)&W_enc[(size_t)(k0 + kr) * F_SZ + n0 + cb + j * 4];
                tile[kr][cb + j * 4 + 0] = v.x;
                tile[kr][cb + j * 4 + 1] = v.y;
                tile[kr][cb + j * 4 + 2] = v.z;
                tile[kr][cb + j * 4 + 3] = v.w;
            }
        }
        __syncthreads();
        const int n = t >> 2;
#pragma unroll
        for (int cc = 0; cc < 2; ++cc) {
            const int ch = (t & 3) * 2 + cc;
            short8v h, l;
#pragma unroll
            for (int e = 0; e < 8; ++e) {
                short hh, ll;
                split_bf16(tile[ch * 8 + e][n], hh, ll);
                h[e] = hh; l[e] = ll;
            }
            size_t off = (size_t)(n0 + n) * D_SZ + k0 + ch * 8;
            *(short8v*)&Wh[off] = h;
            *(short8v*)&Wl[off] = l;
        }
    } else {
        const int id = bid - 2048;
        const int k0 = (id & 7) * 64;
        const int c0 = (id >> 3) * 64;
        for (int idx = t; idx < 64 * 64; idx += 256) {
            const int kr = idx >> 6;
            const int cc = idx & 63;
            tile[kr][cc] = (c0 + cc < C_SZ) ? W_fc[(size_t)(k0 + kr) * C_SZ + c0 + cc] : 0.0f;
        }
        __syncthreads();
        const int crow = t >> 2;
#pragma unroll
        for (int cc2 = 0; cc2 < 2; ++cc2) {
            const int ch = (t & 3) * 2 + cc2;
            short8v h, l;
#pragma unroll
            for (int e = 0; e < 8; ++e) {
                short hh, ll;
                split_bf16(tile[ch * 8 + e][crow], hh, ll);
                h[e] = hh; l[e] = ll;
            }
            size_t off = (size_t)(c0 + crow) * F_SZ + k0 + ch * 8;
            *(short8v*)&Wth[off] = h;
            *(short8v*)&Wtl[off] = l;
        }
    }
}

__global__ __launch_bounds__(256, 1) void gemm_ws128(
    const short* __restrict__ Xh, const short* __restrict__ Xl,
    const short* __restrict__ Wh, const short* __restrict__ Wl,
    float* __restrict__ P, int ksteps)
{
    __shared__ __align__(16) short sAh[2][8192];
    __shared__ __align__(16) short sAl[2][8192];
    __shared__ __align__(16) short sBh[2][8192];
    __shared__ __align__(16) short sBl[2][8192];

    const int t = threadIdx.x;
    const int lane = t & 63;
    const int wave = t >> 6;
    const int nt = blockIdx.x;
    const int mt = blockIdx.y;
    const int ks = blockIdx.z;
    const int m0 = mt * 128;
    const int n0 = nt * 128;
    const int kbase = ks * ksteps * 64;

    const short* gbase =
        (wave == 0) ? Xh + (size_t)m0 * D_SZ :
        (wave == 1) ? Xl + (size_t)m0 * D_SZ :
        (wave == 2) ? Wh + (size_t)n0 * D_SZ :
                      Wl + (size_t)n0 * D_SZ;
    short* lb[2];
    lb[0] = (wave == 0) ? sAh[0] : (wave == 1) ? sAl[0] : (wave == 2) ? sBh[0] : sBl[0];
    lb[1] = (wave == 0) ? sAh[1] : (wave == 1) ? sAl[1] : (wave == 2) ? sBh[1] : sBl[1];
    const int lrow8 = lane >> 3;
    const int gchunkOff = ((lane & 7) ^ lrow8) * 8;
    const short* gsrc = gbase + (size_t)lrow8 * D_SZ + kbase + gchunkOff;

    const int mo = (wave >> 1) * 64;
    const int no = (wave & 1) * 64;
    const int lr = lane & 15;
    const int lkg = lane >> 4;
    const int x7 = lr & 7;
    const int sl0 = lkg ^ x7;
    const int sl1 = (4 + lkg) ^ x7;
    int aoff[4], boff[4];
#pragma unroll
    for (int f = 0; f < 4; ++f) {
        aoff[f] = (mo + 16 * f + lr) * 64;
        boff[f] = (no + 16 * f + lr) * 64;
    }

    f32x4 acc[4][4] = {};

#pragma unroll
    for (int j = 0; j < 16; ++j)
        gl_lds16(gsrc + (size_t)(8 * j) * D_SZ, lb[0] + j * 512);

    int buf = 0;
    for (int s = 0; s < ksteps; ++s) {
        if (s + 1 < ksteps) {
            short* dst = lb[buf ^ 1];
            const short* g = gsrc + (s + 1) * 64;
#pragma unroll
            for (int j = 0; j < 16; ++j)
                gl_lds16(g + (size_t)(8 * j) * D_SZ, dst + j * 512);
            asm volatile("s_waitcnt vmcnt(16)" ::: "memory");
        } else {
            asm volatile("s_waitcnt vmcnt(0)" ::: "memory");
        }
        fence_barrier();

        __builtin_amdgcn_s_setprio(1);
        {
            const short* pAh = sAh[buf];
            const short* pAl = sAl[buf];
            const short* pBh = sBh[buf];
            const short* pBl = sBl[buf];
#pragma unroll
            for (int ksub = 0; ksub < 2; ++ksub) {
                const int sl = ksub ? sl1 : sl0;
                bf16x8 ah[4], al[4], bh[4], blo[4];
#pragma unroll
                for (int f = 0; f < 4; ++f) {
                    ah[f]  = *(const bf16x8*)&pAh[aoff[f] + sl * 8];
                    al[f]  = *(const bf16x8*)&pAl[aoff[f] + sl * 8];
                }
#pragma unroll
                for (int g = 0; g < 4; ++g) {
                    bh[g]  = *(const bf16x8*)&pBh[boff[g] + sl * 8];
                    blo[g] = *(const bf16x8*)&pBl[boff[g] + sl * 8];
                }
#pragma unroll
                for (int f = 0; f < 4; ++f)
#pragma unroll
                    for (int g = 0; g < 4; ++g)
                        acc[f][g] = MFMA_BF16(ah[f], bh[g], acc[f][g], 0, 0, 0);
#pragma unroll
                for (int f = 0; f < 4; ++f)
#pragma unroll
                    for (int g = 0; g < 4; ++g)
                        acc[f][g] = MFMA_BF16(ah[f], blo[g], acc[f][g], 0, 0, 0);
#pragma unroll
                for (int f = 0; f < 4; ++f)
#pragma unroll
                    for (int g = 0; g < 4; ++g)
                        acc[f][g] = MFMA_BF16(al[f], bh[g], acc[f][g], 0, 0, 0);
            }
        }
        __builtin_amdgcn_s_setprio(0);
        fence_barrier();
        buf ^= 1;
    }

    float* Pout = P + (size_t)ks * (2048u * 512u);
#pragma unroll
    for (int f = 0; f < 4; ++f)
#pragma unroll
        for (int g = 0; g < 4; ++g) {
            const int col  = n0 + no + 16 * g + (lane & 15);
            const int row0 = m0 + mo + 16 * f + (lane >> 4) * 4;
#pragma unroll
            for (int r = 0; r < 4; ++r)
                Pout[(size_t)(row0 + r) * F_SZ + col] = acc[f][g][r];
        }
}

__global__ __launch_bounds__(256) void reduce_feats_split(
    const float* __restrict__ P, float* __restrict__ feats,
    short* __restrict__ Fh, short* __restrict__ Fl,
    const float* __restrict__ W_fc,
    short* __restrict__ Wth, short* __restrict__ Wtl)
{
    const int bid = blockIdx.x;
    const int t = threadIdx.x;
    if (bid < 1024) {
        const int n4 = (2048 * 512) / 4;
        const float* P1 = P + 2048 * 512;
        for (int i4 = bid * 256 + t; i4 < n4; i4 += 1024 * 256) {
            float4 a = ((const float4*)P)[i4];
            float4 b = ((const float4*)P1)[i4];
            float v[4] = {a.x + b.x, a.y + b.y, a.z + b.z, a.w + b.w};
            short4v h, l;
            short hh, ll;
#pragma unroll
            for (int e = 0; e < 4; ++e) {
                feats[i4 * 4 + e] = v[e];
                split_bf16(v[e], hh, ll); h[e] = hh; l[e] = ll;
            }
            ((short4v*)Fh)[i4] = h;
            ((short4v*)Fl)[i4] = l;
        }
    } else {
        __shared__ float tile[64][65];
        const int id = bid - 1024;
        const int k0 = (id & 7) * 64;
        const int c0 = (id >> 3) * 64;
        for (int idx = t; idx < 64 * 64; idx += 256) {
            const int kr = idx >> 6;
            const int cc = idx & 63;
            tile[kr][cc] = (c0 + cc < C_SZ) ? W_fc[(size_t)(k0 + kr) * C_SZ + c0 + cc] : 0.0f;
        }
        __syncthreads();
        const int crow = t >> 2;
#pragma unroll
        for (int cc2 = 0; cc2 < 2; ++cc2) {
            const int ch = (t & 3) * 2 + cc2;
            short8v h, l;
#pragma unroll
            for (int e = 0; e < 8; ++e) {
                short hh, ll;
                split_bf16(tile[ch * 8 + e][crow], hh, ll);
                h[e] = hh; l[e] = ll;
            }
            size_t off = (size_t)(c0 + crow) * F_SZ + k0 + ch * 8;
            *(short8v*)&Wth[off] = h;
            *(short8v*)&Wtl[off] = l;
        }
    }
}

__global__ __launch_bounds__(256) void gemm_fc(
    const short* __restrict__ Ah, const short* __restrict__ Al,
    const short* __restrict__ Bh, const short* __restrict__ Bl,
    const float* __restrict__ bias, float* __restrict__ Cout, int M)
{
    __shared__ __align__(16) short sAh[4096];
    __shared__ __align__(16) short sAl[4096];
    __shared__ __align__(16) short sBh[4096];
    __shared__ __align__(16) short sBl[4096];

    const int t = threadIdx.x;
    const int lane = t & 63;
    const int wave = t >> 6;
    const int n0 = blockIdx.x * 64;
    const int m0 = blockIdx.y * 64;

    const int lrow8 = lane >> 3;
    const int colOff = ((lane & 7) ^ lrow8) * 8;

    short* lbase = (wave == 0) ? sAh : (wave == 1) ? sAl : (wave == 2) ? sBh : sBl;
    const short* gA = (wave == 1) ? Al : Ah;
    const short* gB = (wave == 3) ? Bl : Bh;
    const bool isA = wave < 2;

    const int mo = (wave >> 1) * 32;
    const int no = (wave & 1) * 32;
    const int lr = lane & 15;
    const int lkg = lane >> 4;
    const int x7 = lr & 7;
    const int sl0 = (0 + lkg) ^ x7;
    const int sl1 = (4 + lkg) ^ x7;
    const int ra0 = (mo + lr) * 64,      ra1 = (mo + 16 + lr) * 64;
    const int rb0 = (no + lr) * 64,      rb1 = (no + 16 + lr) * 64;
    const int a00 = ra0 + sl0 * 8, a01 = ra0 + sl1 * 8;
    const int a10 = ra1 + sl0 * 8, a11 = ra1 + sl1 * 8;
    const int b00 = rb0 + sl0 * 8, b01 = rb0 + sl1 * 8;
    const int b10 = rb1 + sl0 * 8, b11 = rb1 + sl1 * 8;

    f32x4 acc[2][2] = {};

    for (int s = 0; s < 8; ++s) {
        __syncthreads();
        if (isA) {
#pragma unroll
            for (int j = 0; j < 8; ++j) {
                int row = m0 + lrow8 + 8 * j;
                if (row > M - 1) row = M - 1;
                gl_lds16(gA + (size_t)row * F_SZ + s * 64 + colOff, lbase + j * 512);
            }
        } else {
#pragma unroll
            for (int j = 0; j < 8; ++j) {
                int row = n0 + lrow8 + 8 * j;
                gl_lds16(gB + (size_t)row * F_SZ + s * 64 + colOff, lbase + j * 512);
            }
        }
        __syncthreads();
        MFMA_BLOCK(a00, a10, b00, b10);
        MFMA_BLOCK(a01, a11, b01, b11);
    }

#pragma unroll
    for (int f = 0; f < 2; ++f)
#pragma unroll
        for (int g = 0; g < 2; ++g) {
            const int col  = n0 + no + g * 16 + (lane & 15);
            if (col >= C_SZ) continue;
            const float bb = bias[col];
            const int row0 = m0 + mo + f * 16 + (lane >> 4) * 4;
#pragma unroll
            for (int r = 0; r < 4; ++r) {
                const int row = row0 + r;
                if (row < M)
                    Cout[(size_t)row * C_SZ + col] = acc[f][g][r] + bb;
            }
        }
}

__global__ __launch_bounds__(64) void argmax_labels(
    const float* __restrict__ logits, const float* __restrict__ partial_Y,
    float* __restrict__ labels_f)
{
    const int i = blockIdx.x;
    const int lane = threadIdx.x;
    float best = -FLT_MAX;
    int bidx = C_SZ;
    for (int c = lane; c < C_SZ; c += 64) {
        if (partial_Y[(size_t)i * C_SZ + c] != 0.0f) {
            float v = logits[(size_t)i * C_SZ + c];
            if (v > best || (v == best && c < bidx)) { best = v; bidx = c; }
        }
    }
#pragma unroll
    for (int off = 32; off; off >>= 1) {
        float ov = __shfl_down(best, off);
        int oi = __shfl_down(bidx, off);
        if (ov > best || (ov == best && oi < bidx)) { best = ov; bidx = oi; }
    }
    if (lane == 0) labels_f[i] = (float)bidx;
}

__global__ __launch_bounds__(512) void proto_update(
    const float* __restrict__ labels_f, const float* __restrict__ feats_q,
    const float* __restrict__ proto, float* __restrict__ new_proto,
    short* __restrict__ NPh, short* __restrict__ NPl)
{
    __shared__ int lab[B_SZ];
    __shared__ float red[8];
    __shared__ float rinv_s;
    const int c = blockIdx.x;
    const int t = threadIdx.x;
    for (int i = t; i < B_SZ; i += 512) lab[i] = (int)labels_f[i];
    __syncthreads();
    float val = proto[(size_t)c * F_SZ + t];
    for (int i = 0; i < B_SZ; ++i) {
        if (lab[i] == c)
            val = PROTO_W * val + (1.0f - PROTO_W) * feats_q[(size_t)i * F_SZ + t];
    }
    float sq = val * val;
#pragma unroll
    for (int off = 32; off; off >>= 1) sq += __shfl_down(sq, off);
    if ((t & 63) == 0) red[t >> 6] = sq;
    __syncthreads();
    if (t == 0) {
        float s = 0.0f;
#pragma unroll
        for (int w = 0; w < 8; ++w) s += red[w];
        rinv_s = 1.0f / sqrtf(s);
    }
    __syncthreads();
    const float v = val * rinv_s;
    new_proto[(size_t)c * F_SZ + t] = v;
    if (NPh) {
        short hh, ll;
        split_bf16(v, hh, ll);
        NPh[(size_t)c * F_SZ + t] = hh;
        NPl[(size_t)c * F_SZ + t] = ll;
    }
}

// ---------------------------------------------------------------------------
extern "C" void kernel_launch(void* const* d_in, const int* in_sizes, int n_in,
                              void* d_out, int out_size, void* d_ws, size_t ws_size,
                              hipStream_t stream)
{
    const float* img_q     = (const float*)d_in[0];
    const float* img_q1    = (const float*)d_in[1];
    const float* partial_Y = (const float*)d_in[2];
    const float* W_enc     = (const float*)d_in[3];
    const float* W_fc      = (const float*)d_in[4];
    const float* b_fc      = (const float*)d_in[5];
    const float* proto     = (const float*)d_in[6];

    float* out       = (float*)d_out;
    float* logits    = out;            // [2048][345]
    float* new_proto = out + 706560;   // [345][512]
    float* scores    = out + 883200;   // [345][345]
    float* labels_f  = out + 1002225;  // [1024]
    float* feats     = out + 1003249;  // [2048][512]

    char* ws = (char*)d_ws;
    short* Xh = (short*)(ws + WS_XH);
    short* Xl = (short*)(ws + WS_XL);
    short* Wh = (short*)(ws + WS_WH);
    short* Wl = (short*)(ws + WS_WL);
    float* P  = (float*)(ws + WS_P);

    if (ws_size >= (size_t)WS2_NEED) {
        short* Wth = (short*)(ws + WS2_WFH);
        short* Wtl = (short*)(ws + WS2_WFL);
        unsigned long long* labPack = (unsigned long long*)(ws + WS2_LAB);

        hipLaunchKernelGGL(convert_pack2, dim3(2096), dim3(256), 0, stream,
                           img_q, img_q1, W_enc, W_fc, Xh, Xl, Wh, Wl, Wth, Wtl,
                           labPack);
        hipLaunchKernelGGL(gemm_ws128_v6, dim3(4, 16, 4), dim3(512), 0, stream,
                           Xh, Xl, Wh, Wl, P, feats, labPack);
        hipLaunchKernelGGL(fc_logits4, dim3(6, 32), dim3(256), 0, stream,
                           feats, Wth, Wtl, b_fc, partial_Y, logits, labPack);
        hipLaunchKernelGGL(proto_scores_fused, dim3(345), dim3(512), 0, stream,
                           labPack, feats, proto, Wth, Wtl, b_fc,
                           new_proto, scores, labels_f);
    } else {
        short* Fh  = (short*)(ws + WS_FH);
        short* Fl  = (short*)(ws + WS_FL);
        short* Wth = (short*)(ws + WS_WFH);
        short* Wtl = (short*)(ws + WS_WFL);
        short* NPh = (short*)(ws + WS_NPH);
        short* NPl = (short*)(ws + WS_NPL);

        hipLaunchKernelGGL(convert_all, dim3(2048), dim3(256), 0, stream,
                           img_q, img_q1, W_enc, W_fc, Xh, Xl, Wh, Wl,
                           (short*)nullptr, (short*)nullptr,
                           (unsigned long long*)nullptr);
        hipLaunchKernelGGL(gemm_ws128, dim3(4, 16, 2), dim3(256), 0, stream,
                           Xh, Xl, Wh, Wl, P, 64);
        hipLaunchKernelGGL(reduce_feats_split, dim3(1072), dim3(256), 0, stream,
                           P, feats, Fh, Fl, W_fc, Wth, Wtl);
        hipLaunchKernelGGL(gemm_fc, dim3(6, 32), dim3(256), 0, stream,
                           Fh, Fl, Wth, Wtl, b_fc, logits, 2048);
        hipLaunchKernelGGL(argmax_labels, dim3(1024), dim3(64), 0, stream,
                           logits, partial_Y, labels_f);
        hipLaunchKernelGGL(proto_update, dim3(345), dim3(512), 0, stream,
                           labels_f, feats, proto, new_proto, NPh, NPl);
        hipLaunchKernelGGL(gemm_fc, dim3(6, 6), dim3(256), 0, stream,
                           NPh, NPl, Wth, Wtl, b_fc, scores, C_SZ);
    }
}

// Round 8
// 246.952 us; speedup vs baseline: 1.2821x; 1.2821x over previous
//
#include <hip/hip_runtime.h>
#include <float.h>
#include <math.h>

// Problem constants
#define B_SZ 1024
#define D_SZ 8192
#define C_SZ 345
#define F_SZ 512
#define PROTO_W 0.99f

// d_out layout (float32, flat, reference return order):
//   logits   [2048][345]  @ 0
//   new_proto[345][512]   @ 706560
//   scores   [345][345]   @ 883200
//   labels   [1024]       @ 1002225  (stored as float)
//   feats    [2048][512]  @ 1003249

// ---------------- NEW-path d_ws layout -----------
// R14: Xh/Xl hold packed A tiles [mt 0..15][kstep32 0..255][4096 shorts];
// Wh/Wl packed B tiles [nt 0..3][kstep32 0..255][4096 shorts].
#define WS_XH 0
#define WS_XL 33554432u
#define WS_WH 67108864u
#define WS_WL 75497472u
#define WS_P  83886080u
#define WS2_WFH 100663296u
#define WS2_WFL 101056512u
#define WS2_LAB 101449728u
#define WS2_NEED 101457920u

// ---------------- OLD-path (R6 fallback) overlay offsets ---------------------
#define WS_NEED 92274688u
#define WS_FH  0u
#define WS_FL  2097152u
#define WS_WFH 4194304u
#define WS_WFL 4587520u
#define WS_NPH 4980736u
#define WS_NPL 5373952u

typedef short bf16x8 __attribute__((ext_vector_type(8)));
typedef short short4v __attribute__((ext_vector_type(4)));
typedef short short8v __attribute__((ext_vector_type(8)));
typedef float f32x4  __attribute__((ext_vector_type(4)));

__device__ __forceinline__ void split_bf16(float x, short& hi, short& lo) {
    unsigned u = __float_as_uint(x);
    unsigned r = (u + 0x7FFFu + ((u >> 16) & 1u)) >> 16;
    hi = (short)r;
    float hf = __uint_as_float(r << 16);
    lo = (short)(__float_as_uint(x - hf) >> 16);
}
__device__ __forceinline__ float bf16_f32(short h) {
    return __uint_as_float(((unsigned)(unsigned short)h) << 16);
}

__device__ __forceinline__ void gl_lds16(const short* g, short* l) {
    __builtin_amdgcn_global_load_lds(
        (const __attribute__((address_space(1))) void*)g,
        (__attribute__((address_space(3))) void*)l, 16, 0, 0);
}

// order-preserving float -> u32 key (larger float => larger key)
__device__ __forceinline__ unsigned f2key(float v) {
    unsigned u = __float_as_uint(v);
    return (u & 0x80000000u) ? ~u : (u | 0x80000000u);
}

// Raw barrier with compiler memory fence but NO hardware counter drain.
__device__ __forceinline__ void fence_barrier() {
    asm volatile("" ::: "memory");
    __builtin_amdgcn_s_barrier();
    asm volatile("" ::: "memory");
}

#define MFMA_BF16 __builtin_amdgcn_mfma_f32_16x16x32_bf16

// 12-MFMA bf16x3 block (2x2 frags); expects sAh/sAl/sBh/sBl + acc in scope.
#define MFMA_BLOCK(IA0, IA1, IB0, IB1)                                   \
    do {                                                                 \
        bf16x8 a0h = *(const bf16x8*)&sAh[IA0];                          \
        bf16x8 a1h = *(const bf16x8*)&sAh[IA1];                          \
        bf16x8 b0h = *(const bf16x8*)&sBh[IB0];                          \
        bf16x8 b1h = *(const bf16x8*)&sBh[IB1];                          \
        bf16x8 a0l = *(const bf16x8*)&sAl[IA0];                          \
        bf16x8 a1l = *(const bf16x8*)&sAl[IA1];                          \
        bf16x8 b0l = *(const bf16x8*)&sBl[IB0];                          \
        bf16x8 b1l = *(const bf16x8*)&sBl[IB1];                          \
        acc[0][0] = MFMA_BF16(a0h, b0h, acc[0][0], 0, 0, 0);             \
        acc[0][1] = MFMA_BF16(a0h, b1h, acc[0][1], 0, 0, 0);             \
        acc[1][0] = MFMA_BF16(a1h, b0h, acc[1][0], 0, 0, 0);             \
        acc[1][1] = MFMA_BF16(a1h, b1h, acc[1][1], 0, 0, 0);             \
        acc[0][0] = MFMA_BF16(a0h, b0l, acc[0][0], 0, 0, 0);             \
        acc[0][1] = MFMA_BF16(a0h, b1l, acc[0][1], 0, 0, 0);             \
        acc[1][0] = MFMA_BF16(a1h, b0l, acc[1][0], 0, 0, 0);             \
        acc[1][1] = MFMA_BF16(a1h, b1l, acc[1][1], 0, 0, 0);             \
        acc[0][0] = MFMA_BF16(a0l, b0h, acc[0][0], 0, 0, 0);             \
        acc[0][1] = MFMA_BF16(a0l, b1h, acc[0][1], 0, 0, 0);             \
        acc[1][0] = MFMA_BF16(a1l, b0h, acc[1][0], 0, 0, 0);             \
        acc[1][1] = MFMA_BF16(a1l, b1h, acc[1][1], 0, 0, 0);             \
    } while (0)

// ---------------------------------------------------------------------------
// R14 packed layout: per (128-row-group, 32-k) tile = 4096 shorts.
// Element (pr 0..127, k 0..31): half = pr>>6, r = pr&63, rp = r>>1, p = r&1,
// c = k>>3, slot = ((p<<2)|c) ^ (rp&7):
//   off = half*2048 + rp*64 + slot*8 + (k&7)
// ---------------------------------------------------------------------------

// ---------------------------------------------------------------------------
// convert_pack2: X -> packed A tiles; W_enc -> packed B tiles;
// W_fc -> Wth/Wtl (unchanged layout); zeroes labPack. grid 2096 x 256.
// ---------------------------------------------------------------------------
__global__ __launch_bounds__(256) void convert_pack2(
    const float* __restrict__ img_q, const float* __restrict__ img_q1,
    const float* __restrict__ W_enc, const float* __restrict__ W_fc,
    short* __restrict__ Ahp, short* __restrict__ Alp,
    short* __restrict__ Bhp, short* __restrict__ Blp,
    short* __restrict__ Wth, short* __restrict__ Wtl,
    unsigned long long* __restrict__ labPack)
{
    __shared__ float tile[64][65];
    const int bid = blockIdx.x;
    const int t = threadIdx.x;

    if (bid < 4)
        labPack[bid * 256 + t] = 0ull;

    if (bid < 1024) {
        const int total = 2048 * 1024;
        for (int i = bid * 256 + t; i < total; i += 1024 * 256) {
            const int row = i >> 10;
            const int cc = i & 1023;
            const float* src = (row < B_SZ)
                ? &img_q[(size_t)row * D_SZ + cc * 8]
                : &img_q1[(size_t)(row - B_SZ) * D_SZ + cc * 8];
            float4 a = ((const float4*)src)[0];
            float4 b = ((const float4*)src)[1];
            float f[8] = {a.x, a.y, a.z, a.w, b.x, b.y, b.z, b.w};
            short8v h, l;
#pragma unroll
            for (int e = 0; e < 8; ++e) {
                short hh, ll;
                split_bf16(f[e], hh, ll);
                h[e] = hh; l[e] = ll;
            }
            const int mt = row >> 7;
            const int pr = row & 127;
            const int kstep = cc >> 2;
            const int c = cc & 3;
            const int hf = pr >> 6;
            const int r = pr & 63;
            const int rp = r >> 1;
            const int slot = (((r & 1) << 2) | c) ^ (rp & 7);
            const size_t dst = (size_t)(mt * 256 + kstep) * 4096
                             + hf * 2048 + rp * 64 + slot * 8;
            *(short8v*)&Ahp[dst] = h;
            *(short8v*)&Alp[dst] = l;
        }
    } else if (bid < 2048) {
        const int id = bid - 1024;
        const int kstep64 = id >> 3;
        const int k0 = kstep64 * 64;
        const int n0 = (id & 7) * 64;
        {
            const int kr = t >> 2;
            const int cb = (t & 3) * 16;
#pragma unroll
            for (int j = 0; j < 4; ++j) {
                float4 v = *(const float4*)&W_enc[(size_t)(k0 + kr) * F_SZ + n0 + cb + j * 4];
                tile[kr][cb + j * 4 + 0] = v.x;
                tile[kr][cb + j * 4 + 1] = v.y;
                tile[kr][cb + j * 4 + 2] = v.z;
                tile[kr][cb + j * 4 + 3] = v.w;
            }
        }
        __syncthreads();
        const int n = t >> 2;
#pragma unroll
        for (int cc2 = 0; cc2 < 2; ++cc2) {
            const int ch = (t & 3) * 2 + cc2;
            short8v h, l;
#pragma unroll
            for (int e = 0; e < 8; ++e) {
                short hh, ll;
                split_bf16(tile[ch * 8 + e][n], hh, ll);
                h[e] = hh; l[e] = ll;
            }
            const int nrow = n0 + n;
            const int k32 = kstep64 * 2 + (ch >> 2);
            const int c = ch & 3;
            const int nt_ = nrow >> 7;
            const int pr = nrow & 127;
            const int hf = pr >> 6;
            const int r = pr & 63;
            const int rp = r >> 1;
            const int slot = (((r & 1) << 2) | c) ^ (rp & 7);
            const size_t dst = (size_t)(nt_ * 256 + k32) * 4096
                             + hf * 2048 + rp * 64 + slot * 8;
            *(short8v*)&Bhp[dst] = h;
            *(short8v*)&Blp[dst] = l;
        }
    } else {
        const int id = bid - 2048;
        const int k0 = (id & 7) * 64;
        const int c0 = (id >> 3) * 64;
        for (int idx = t; idx < 64 * 64; idx += 256) {
            const int kr = idx >> 6;
            const int cc = idx & 63;
            tile[kr][cc] = (c0 + cc < C_SZ) ? W_fc[(size_t)(k0 + kr) * C_SZ + c0 + cc] : 0.0f;
        }
        __syncthreads();
        const int crow = t >> 2;
#pragma unroll
        for (int cc2 = 0; cc2 < 2; ++cc2) {
            const int ch = (t & 3) * 2 + cc2;
            short8v h, l;
#pragma unroll
            for (int e = 0; e < 8; ++e) {
                short hh, ll;
                split_bf16(tile[ch * 8 + e][crow], hh, ll);
                h[e] = hh; l[e] = ll;
            }
            size_t off = (size_t)(c0 + crow) * F_SZ + k0 + ch * 8;
            *(short8v*)&Wth[off] = h;
            *(short8v*)&Wtl[off] = l;
        }
    }
}

// ---------------------------------------------------------------------------
// gemm_ws128_v5 (R14, proven 49 µs): deep pipeline — BK=32, 4 LDS buffers,
// depth-3 prefetch, ONE barrier per step, steady vmcnt(8), setprio.
// NO fused reduction (R7 showed the per-block device fence costs 100 µs —
// cross-XCD L2 non-coherence makes intra-launch producer/consumer toxic).
// grid (4,16,4) x 512 threads.
// ---------------------------------------------------------------------------
#define V5_MFMA(PAH, PAL, PBH, PBL)                                          \
    do {                                                                     \
        bf16x8 ah[4], al[4], bh_[2], bl_[2];                                 \
        _Pragma("unroll")                                                    \
        for (int f = 0; f < 4; ++f) {                                        \
            ah[f] = *(const bf16x8*)&(PAH)[aoff[f]];                         \
            al[f] = *(const bf16x8*)&(PAL)[aoff[f]];                         \
        }                                                                    \
        _Pragma("unroll")                                                    \
        for (int g = 0; g < 2; ++g) {                                        \
            bh_[g] = *(const bf16x8*)&(PBH)[boff[g]];                        \
            bl_[g] = *(const bf16x8*)&(PBL)[boff[g]];                        \
        }                                                                    \
        __builtin_amdgcn_s_setprio(1);                                       \
        _Pragma("unroll")                                                    \
        for (int f = 0; f < 4; ++f)                                          \
            _Pragma("unroll")                                                \
            for (int g = 0; g < 2; ++g)                                      \
                acc[f][g] = MFMA_BF16(ah[f], bh_[g], acc[f][g], 0, 0, 0);    \
        _Pragma("unroll")                                                    \
        for (int f = 0; f < 4; ++f)                                          \
            _Pragma("unroll")                                                \
            for (int g = 0; g < 2; ++g)                                      \
                acc[f][g] = MFMA_BF16(ah[f], bl_[g], acc[f][g], 0, 0, 0);    \
        _Pragma("unroll")                                                    \
        for (int f = 0; f < 4; ++f)                                          \
            _Pragma("unroll")                                                \
            for (int g = 0; g < 2; ++g)                                      \
                acc[f][g] = MFMA_BF16(al[f], bh_[g], acc[f][g], 0, 0, 0);    \
        __builtin_amdgcn_s_setprio(0);                                       \
    } while (0)

#define V5_STEP(BI, SD, SW, VMLIT)                                           \
    do {                                                                     \
        asm volatile("s_waitcnt vmcnt(" VMLIT ")" ::: "memory");             \
        fence_barrier();                                                     \
        {                                                                    \
            const short* gg = gsrc0 + (size_t)(SW) * 4096;                   \
            gl_lds16(gg, SD);                                                \
            gl_lds16(gg + 512, (SD) + 512);                                  \
            gl_lds16(gg + 1024, (SD) + 1024);                                \
            gl_lds16(gg + 1536, (SD) + 1536);                                \
        }                                                                    \
        V5_MFMA(SAh[BI], SAl[BI], SBh[BI], SBl[BI]);                         \
    } while (0)

#define V5_STEPN(BI, VMLIT)                                                  \
    do {                                                                     \
        asm volatile("s_waitcnt vmcnt(" VMLIT ")" ::: "memory");             \
        fence_barrier();                                                     \
        V5_MFMA(SAh[BI], SAl[BI], SBh[BI], SBl[BI]);                         \
    } while (0)

__global__ __launch_bounds__(512, 1) void gemm_ws128_v5(
    const short* __restrict__ Ahp, const short* __restrict__ Alp,
    const short* __restrict__ Bhp, const short* __restrict__ Blp,
    float* __restrict__ P)
{
    __shared__ __align__(16) short SAh[4][4096];
    __shared__ __align__(16) short SAl[4][4096];
    __shared__ __align__(16) short SBh[4][4096];
    __shared__ __align__(16) short SBl[4][4096];

    const int t = threadIdx.x;
    const int lane = t & 63;
    const int wave = t >> 6;

    // XCD-aware bijective swizzle (flat id, nwg = 256)
    const int flat = blockIdx.x + 4 * blockIdx.y + 64 * blockIdx.z;
    const int logical = (flat & 7) * 32 + (flat >> 3);
    const int nt = logical & 3;
    const int mt = (logical >> 2) & 15;
    const int ks = logical >> 6;

    const int m0 = mt * 128;
    const int n0 = nt * 128;

    const int arr = wave >> 1;
    const int half = wave & 1;
    const short* gtile =
        (arr == 0) ? Ahp + (size_t)(mt * 256) * 4096 :
        (arr == 1) ? Alp + (size_t)(mt * 256) * 4096 :
        (arr == 2) ? Bhp + (size_t)(nt * 256) * 4096 :
                     Blp + (size_t)(nt * 256) * 4096;
    const short* gsrc0 = gtile + (size_t)(ks * 64) * 4096 + half * 2048 + lane * 8;

    short* abase =
        (arr == 0) ? &SAh[0][0] : (arr == 1) ? &SAl[0][0] :
        (arr == 2) ? &SBh[0][0] : &SBl[0][0];
    short* sd0 = abase + 0 * 4096 + half * 2048;
    short* sd1 = abase + 1 * 4096 + half * 2048;
    short* sd2 = abase + 2 * 4096 + half * 2048;
    short* sd3 = abase + 3 * 4096 + half * 2048;

    const int wr = wave >> 2;
    const int wc = wave & 3;
    const int mo = wr * 64;
    const int no = wc * 32;
    const int lr = lane & 15;
    const int lkg = lane >> 4;
    int aoff[4], boff[2];
#pragma unroll
    for (int f = 0; f < 4; ++f) {
        const int R = mo + 16 * f + lr;
        const int r = R & 63;
        const int rp = r >> 1;
        aoff[f] = (R >> 6) * 2048 + rp * 64
                + (((((r & 1) << 2) | lkg)) ^ (rp & 7)) * 8;
    }
#pragma unroll
    for (int g = 0; g < 2; ++g) {
        const int R = no + 16 * g + lr;
        const int r = R & 63;
        const int rp = r >> 1;
        boff[g] = (R >> 6) * 2048 + rp * 64
                + (((((r & 1) << 2) | lkg)) ^ (rp & 7)) * 8;
    }

    f32x4 acc[4][2] = {};

    // prologue: stage steps 0,1,2 into buffers 0,1,2 (12 loads in flight)
    {
        gl_lds16(gsrc0,        sd0);
        gl_lds16(gsrc0 + 512,  sd0 + 512);
        gl_lds16(gsrc0 + 1024, sd0 + 1024);
        gl_lds16(gsrc0 + 1536, sd0 + 1536);
        const short* g1 = gsrc0 + 4096;
        gl_lds16(g1,        sd1);
        gl_lds16(g1 + 512,  sd1 + 512);
        gl_lds16(g1 + 1024, sd1 + 1024);
        gl_lds16(g1 + 1536, sd1 + 1536);
        const short* g2 = gsrc0 + 8192;
        gl_lds16(g2,        sd2);
        gl_lds16(g2 + 512,  sd2 + 512);
        gl_lds16(g2 + 1024, sd2 + 1024);
        gl_lds16(g2 + 1536, sd2 + 1536);
    }

    // main: steps 0..59 (steady state: vmcnt(8), issue s+3 after barrier)
    for (int s4 = 0; s4 < 15; ++s4) {
        const int sb = s4 * 4;
        V5_STEP(0, sd3, sb + 3, "8");
        V5_STEP(1, sd0, sb + 4, "8");
        V5_STEP(2, sd1, sb + 5, "8");
        V5_STEP(3, sd2, sb + 6, "8");
    }
    // peeled tail: s = 60..63
    V5_STEP (0, sd3, 63, "8");
    V5_STEPN(1, "8");
    V5_STEPN(2, "4");
    V5_STEPN(3, "0");

    float* Pout = P + (size_t)ks * (2048u * 512u);
#pragma unroll
    for (int f = 0; f < 4; ++f)
#pragma unroll
        for (int g = 0; g < 2; ++g) {
            const int col  = n0 + no + 16 * g + (lane & 15);
            const int row0 = m0 + mo + 16 * f + (lane >> 4) * 4;
#pragma unroll
            for (int r = 0; r < 4; ++r)
                Pout[(size_t)(row0 + r) * F_SZ + col] = acc[f][g][r];
        }
}

// ---------------------------------------------------------------------------
// reduce_feats4_f32 (R16): sum the 4 split-K P slices once -> feats fp32
// ONLY (fc_logits4 consumes fp32 feats directly; Fh/Fl eliminated).
// Same summation order -> bit-identical. grid 1024 x 256.
// ---------------------------------------------------------------------------
__global__ __launch_bounds__(256) void reduce_feats4_f32(
    const float* __restrict__ P, float* __restrict__ feats)
{
    const int i4 = blockIdx.x * 256 + threadIdx.x;
    float4 a = ((const float4*)P)[i4];
#pragma unroll
    for (int sl = 1; sl < 4; ++sl) {
        float4 b = ((const float4*)(P + (size_t)sl * (2048u * 512u)))[i4];
        a.x += b.x; a.y += b.y; a.z += b.z; a.w += b.w;
    }
    ((float4*)feats)[i4] = a;
}

// ---------------------------------------------------------------------------
// fc_logits4 (kept from R15 — it outperformed fc_logits3 by ~15 µs):
// logits = feats @ W_fc^T + bias, A staged from fp32 feats (reg-load ->
// split_bf16 -> ds_write into the SAME swizzled LDS slots -> bit-identical
// MFMA inputs). Waves 0/1 stage A (T14 issue-early/write-late), waves 2/3
// keep the gl_lds B path. Fused packed-atomicMax masked argmax. grid (6,32).
// ---------------------------------------------------------------------------
__global__ __launch_bounds__(256, 2) void fc_logits4(
    const float* __restrict__ feats,
    const short* __restrict__ Bh_g, const short* __restrict__ Bl_g,
    const float* __restrict__ bias, const float* __restrict__ partial_Y,
    float* __restrict__ logits, unsigned long long* __restrict__ labPack)
{
    __shared__ __align__(16) short dAh[2][4096];
    __shared__ __align__(16) short dAl[2][4096];
    __shared__ __align__(16) short dBh[2][4096];
    __shared__ __align__(16) short dBl[2][4096];

    const int t = threadIdx.x;
    const int lane = t & 63;
    const int wave = t >> 6;
    const int n0 = blockIdx.x * 64;
    const int m0 = blockIdx.y * 64;

    const int lrow8 = lane >> 3;
    const int cg = (lane & 7) ^ lrow8;     // col group 0..7 (swizzled source)
    const bool isA = (wave < 2);

    // B staging (waves 2/3): unchanged gl_lds path
    const short* gB = (wave == 2) ? Bh_g : Bl_g;
    short* lbB[2];
    lbB[0] = (wave == 2) ? dBh[0] : dBl[0];
    lbB[1] = (wave == 2) ? dBh[1] : dBl[1];
    const short* gbaseB = gB + (size_t)(n0 + lrow8) * F_SZ + cg * 8;

    // A staging (waves 0/1): j = wave*4 + j2, row = m0 + lrow8 + 8*j
    const float* gA0 = feats + (size_t)(m0 + lrow8 + 8 * (wave * 4)) * F_SZ + cg * 8;

    // compute role (identical to fc_logits3)
    const int mo = (wave >> 1) * 32;
    const int no = (wave & 1) * 32;
    const int lr = lane & 15;
    const int lkg = lane >> 4;
    const int x7 = lr & 7;
    const int sl0 = (0 + lkg) ^ x7;
    const int sl1 = (4 + lkg) ^ x7;
    const int ra0 = (mo + lr) * 64,      ra1 = (mo + 16 + lr) * 64;
    const int rb0 = (no + lr) * 64,      rb1 = (no + 16 + lr) * 64;
    const int a00 = ra0 + sl0 * 8, a01 = ra0 + sl1 * 8;
    const int a10 = ra1 + sl0 * 8, a11 = ra1 + sl1 * 8;
    const int b00 = rb0 + sl0 * 8, b01 = rb0 + sl1 * 8;
    const int b10 = rb1 + sl0 * 8, b11 = rb1 + sl1 * 8;

    f32x4 acc[2][2] = {};

    // prologue: stage buf0 (s = 0)
    if (isA) {
#pragma unroll
        for (int j2 = 0; j2 < 4; ++j2) {
            const float* src = gA0 + (size_t)(8 * j2) * F_SZ;
            float4 v0 = ((const float4*)src)[0];
            float4 v1 = ((const float4*)src)[1];
            float f8[8] = {v0.x, v0.y, v0.z, v0.w, v1.x, v1.y, v1.z, v1.w};
            bf16x8 h, l;
#pragma unroll
            for (int e = 0; e < 8; ++e) {
                short hh, ll;
                split_bf16(f8[e], hh, ll);
                h[e] = hh; l[e] = ll;
            }
            const int j = wave * 4 + j2;
            *(bf16x8*)&dAh[0][j * 512 + lane * 8] = h;
            *(bf16x8*)&dAl[0][j * 512 + lane * 8] = l;
        }
        asm volatile("s_waitcnt lgkmcnt(0)" ::: "memory");
    } else {
#pragma unroll
        for (int j = 0; j < 8; ++j)
            gl_lds16(gbaseB + (size_t)(8 * j) * F_SZ, lbB[0] + j * 512);
    }

    int buf = 0;
    for (int s = 0; s < 8; ++s) {
        float4 ra[4][2];
        if (isA) {
            if (s + 1 < 8) {
                // issue-early: fp32 loads for step s+1 (arrive under MFMA)
#pragma unroll
                for (int j2 = 0; j2 < 4; ++j2) {
                    const float* src = gA0 + (size_t)(8 * j2) * F_SZ + (s + 1) * 64;
                    ra[j2][0] = ((const float4*)src)[0];
                    ra[j2][1] = ((const float4*)src)[1];
                }
            }
        } else {
            if (s + 1 < 8) {
                short* dst = lbB[buf ^ 1];
                const short* g = gbaseB + (s + 1) * 64;
#pragma unroll
                for (int j = 0; j < 8; ++j)
                    gl_lds16(g + (size_t)(8 * j) * F_SZ, dst + j * 512);
                asm volatile("s_waitcnt vmcnt(8)" ::: "memory");
            } else {
                asm volatile("s_waitcnt vmcnt(0)" ::: "memory");
            }
        }
        fence_barrier();   // buf (step s) fully staged for all waves
        __builtin_amdgcn_s_setprio(1);
        {
            const short* sAh = dAh[buf];
            const short* sAl = dAl[buf];
            const short* sBh = dBh[buf];
            const short* sBl = dBl[buf];
            MFMA_BLOCK(a00, a10, b00, b10);
            MFMA_BLOCK(a01, a11, b01, b11);
        }
        __builtin_amdgcn_s_setprio(0);
        if (isA && s + 1 < 8) {
            // write-late: regs -> split -> ds_write into buf^1
            asm volatile("s_waitcnt vmcnt(0)" ::: "memory");
#pragma unroll
            for (int j2 = 0; j2 < 4; ++j2) {
                float f8[8] = {ra[j2][0].x, ra[j2][0].y, ra[j2][0].z, ra[j2][0].w,
                               ra[j2][1].x, ra[j2][1].y, ra[j2][1].z, ra[j2][1].w};
                bf16x8 h, l;
#pragma unroll
                for (int e = 0; e < 8; ++e) {
                    short hh, ll;
                    split_bf16(f8[e], hh, ll);
                    h[e] = hh; l[e] = ll;
                }
                const int j = wave * 4 + j2;
                *(bf16x8*)&dAh[buf ^ 1][j * 512 + lane * 8] = h;
                *(bf16x8*)&dAl[buf ^ 1][j * 512 + lane * 8] = l;
            }
            asm volatile("s_waitcnt lgkmcnt(0)" ::: "memory");
        }
        fence_barrier();   // readers of buf done; A-writes to buf^1 drained
        buf ^= 1;
    }

    const bool doArg = (m0 < B_SZ);
#pragma unroll
    for (int f = 0; f < 2; ++f) {
#pragma unroll
        for (int r = 0; r < 4; ++r) {
            const int row = m0 + mo + f * 16 + (lane >> 4) * 4 + r;
            unsigned long long best = 0;
#pragma unroll
            for (int g = 0; g < 2; ++g) {
                const int col = n0 + no + g * 16 + (lane & 15);
                if (col < C_SZ) {
                    const float v = acc[f][g][r] + bias[col];
                    logits[(size_t)row * C_SZ + col] = v;
                    if (doArg && partial_Y[(size_t)row * C_SZ + col] != 0.0f) {
                        unsigned long long p = ((unsigned long long)f2key(v) << 32)
                                             | (unsigned long long)(0xFFFFFFFFu - (unsigned)col);
                        if (p > best) best = p;
                    }
                }
            }
            if (doArg) {
#pragma unroll
                for (int m = 1; m < 16; m <<= 1) {
                    unsigned long long o = __shfl_xor(best, m);
                    if (o > best) best = o;
                }
                if ((lane & 15) == 0 && best != 0)
                    atomicMax(&labPack[row], best);
            }
        }
    }
}

// ---------------------------------------------------------------------------
// proto_scores_fused: per class c — ballot-decode labPack, ordered EMA,
// L2 renorm, coalesced scores row. grid 345, 512 threads.
// ---------------------------------------------------------------------------
__global__ __launch_bounds__(512) void proto_scores_fused(
    const unsigned long long* __restrict__ labPack,
    const float* __restrict__ feats_q,
    const float* __restrict__ proto,
    const short* __restrict__ Wth, const short* __restrict__ Wtl,
    const float* __restrict__ b_fc,
    float* __restrict__ new_proto, float* __restrict__ scores,
    float* __restrict__ labels_f)
{
    __shared__ int rowlist[B_SZ];
    __shared__ int mcount_s;
    __shared__ float nprow[F_SZ];
    __shared__ float red[8];
    __shared__ float rinv_s;
    const int c = blockIdx.x;
    const int t = threadIdx.x;
    const int lane = t & 63;
    const int w = t >> 6;

    if (c == 0) {
#pragma unroll
        for (int j = 0; j < 2; ++j) {
            const int i = t + j * 512;
            int li = (int)(0xFFFFFFFFu - (unsigned)(labPack[i] & 0xFFFFFFFFull));
            labels_f[i] = (float)li;
        }
    }

    if (w == 0) {
        int k = 0;
#pragma unroll
        for (int ch = 0; ch < 16; ++ch) {
            unsigned long long pk = labPack[ch * 64 + lane];
            int li = (int)(0xFFFFFFFFu - (unsigned)(pk & 0xFFFFFFFFull));
            unsigned long long mask = __ballot(li == c);
            if (lane == 0) {
                while (mask) {
                    int p = __builtin_ctzll(mask);
                    mask &= mask - 1;
                    rowlist[k++] = ch * 64 + p;
                }
            }
            k = __shfl(k, 0);
        }
        if (lane == 0) mcount_s = k;
    }
    __syncthreads();
    const int m = mcount_s;

    float val = proto[(size_t)c * F_SZ + t];
    for (int k = 0; k < m; ++k)
        val = PROTO_W * val + (1.0f - PROTO_W) * feats_q[(size_t)rowlist[k] * F_SZ + t];

    float sq = val * val;
#pragma unroll
    for (int off = 32; off; off >>= 1) sq += __shfl_down(sq, off);
    if ((t & 63) == 0) red[t >> 6] = sq;
    __syncthreads();
    if (t == 0) {
        float s = 0.0f;
#pragma unroll
        for (int ww = 0; ww < 8; ++ww) s += red[ww];
        rinv_s = 1.0f / sqrtf(s);
    }
    __syncthreads();
    const float v = val * rinv_s;
    new_proto[(size_t)c * F_SZ + t] = v;
    nprow[t] = v;
    __syncthreads();

    float np8[8];
#pragma unroll
    for (int j = 0; j < 8; ++j) np8[j] = nprow[lane * 8 + j];
    for (int col = w; col < C_SZ; col += 8) {
        const short8v h = *(const short8v*)&Wth[(size_t)col * F_SZ + lane * 8];
        const short8v l = *(const short8v*)&Wtl[(size_t)col * F_SZ + lane * 8];
        float p = 0.0f;
#pragma unroll
        for (int j = 0; j < 8; ++j)
            p += np8[j] * (bf16_f32(h[j]) + bf16_f32(l[j]));
#pragma unroll
        for (int off = 32; off; off >>= 1) p += __shfl_down(p, off);
        if (lane == 0) scores[(size_t)c * C_SZ + col] = p + b_fc[col];
    }
}

// ===========================================================================
// OLD-path kernels (R6-proven fallback; used when ws < WS2_NEED)
// ===========================================================================
__global__ __launch_bounds__(256) void convert_all(
    const float* __restrict__ img_q, const float* __restrict__ img_q1,
    const float* __restrict__ W_enc, const float* __restrict__ W_fc,
    short* __restrict__ Xh, short* __restrict__ Xl,
    short* __restrict__ Wh, short* __restrict__ Wl,
    short* __restrict__ Wth, short* __restrict__ Wtl,
    unsigned long long* __restrict__ labPack)
{
    __shared__ float tile[64][65];
    const int bid = blockIdx.x;
    const int t = threadIdx.x;

    if (labPack && bid < 4)
        labPack[bid * 256 + t] = 0ull;

    if (bid < 1024) {
        const int HALF = (B_SZ * D_SZ) / 4;
        const int total = 2 * HALF;
        for (int i4 = bid * 256 + t; i4 < total; i4 += 1024 * 256) {
            float4 v = (i4 < HALF) ? ((const float4*)img_q)[i4]
                                   : ((const float4*)img_q1)[i4 - HALF];
            short4v h, l;
            short hh, ll;
            split_bf16(v.x, hh, ll); h.x = hh; l.x = ll;
            split_bf16(v.y, hh, ll); h.y = hh; l.y = ll;
            split_bf16(v.z, hh, ll); h.z = hh; l.z = ll;
            split_bf16(v.w, hh, ll); h.w = hh; l.w = ll;
            ((short4v*)Xh)[i4] = h;
            ((short4v*)Xl)[i4] = l;
        }
    } else if (bid < 2048) {
        const int id = bid - 1024;
        const int k0 = (id >> 3) * 64;
        const int n0 = (id & 7) * 64;
        {
            const int kr = t >> 2;
            const int cb = (t & 3) * 16;
#pragma unroll
            for (int j = 0; j < 4; ++j) {
                float4 v = *(const float4*)&W_enc[(size_t)(k0 + kr) * F_SZ + n0 + cb + j * 4];
                tile[kr][cb + j * 4 + 0] = v.x;
                tile[kr][cb + j * 4 + 1] = v.y;
                tile[kr][cb + j * 4 + 2] = v.z;
                tile[kr][cb + j * 4 + 3] = v.w;
            }
        }
        __syncthreads();
        const int n = t >> 2;
#pragma unroll
        for (int cc = 0; cc < 2; ++cc) {
            const int ch = (t & 3) * 2 + cc;
            short8v h, l;
#pragma unroll
            for (int e = 0; e < 8; ++e) {
                short hh, ll;
                split_bf16(tile[ch * 8 + e][n], hh, ll);
                h[e] = hh; l[e] = ll;
            }
            size_t off = (size_t)(n0 + n) * D_SZ + k0 + ch * 8;
            *(short8v*)&Wh[off] = h;
            *(short8v*)&Wl[off] = l;
        }
    } else {
        const int id = bid - 2048;
        const int k0 = (id & 7) * 64;
        const int c0 = (id >> 3) * 64;
        for (int idx = t; idx < 64 * 64; idx += 256) {
            const int kr = idx >> 6;
            const int cc = idx & 63;
            tile[kr][cc] = (c0 + cc < C_SZ) ? W_fc[(size_t)(k0 + kr) * C_SZ + c0 + cc] : 0.0f;
        }
        __syncthreads();
        const int crow = t >> 2;
#pragma unroll
        for (int cc2 = 0; cc2 < 2; ++cc2) {
            const int ch = (t & 3) * 2 + cc2;
            short8v h, l;
#pragma unroll
            for (int e = 0; e < 8; ++e) {
                short hh, ll;
                split_bf16(tile[ch * 8 + e][crow], hh, ll);
                h[e] = hh; l[e] = ll;
            }
            size_t off = (size_t)(c0 + crow) * F_SZ + k0 + ch * 8;
            *(short8v*)&Wth[off] = h;
            *(short8v*)&Wtl[off] = l;
        }
    }
}

__global__ __launch_bounds__(256, 1) void gemm_ws128(
    const short* __restrict__ Xh, const short* __restrict__ Xl,
    const short* __restrict__ Wh, const short* __restrict__ Wl,
    float* __restrict__ P, int ksteps)
{
    __shared__ __align__(16) short sAh[2][8192];
    __shared__ __align__(16) short sAl[2][8192];
    __shared__ __align__(16) short sBh[2][8192];
    __shared__ __align__(16) short sBl[2][8192];

    const int t = threadIdx.x;
    const int lane = t & 63;
    const int wave = t >> 6;
    const int nt = blockIdx.x;
    const int mt = blockIdx.y;
    const int ks = blockIdx.z;
    const int m0 = mt * 128;
    const int n0 = nt * 128;
    const int kbase = ks * ksteps * 64;

    const short* gbase =
        (wave == 0) ? Xh + (size_t)m0 * D_SZ :
        (wave == 1) ? Xl + (size_t)m0 * D_SZ :
        (wave == 2) ? Wh + (size_t)n0 * D_SZ :
                      Wl + (size_t)n0 * D_SZ;
    short* lb[2];
    lb[0] = (wave == 0) ? sAh[0] : (wave == 1) ? sAl[0] : (wave == 2) ? sBh[0] : sBl[0];
    lb[1] = (wave == 0) ? sAh[1] : (wave == 1) ? sAl[1] : (wave == 2) ? sBh[1] : sBl[1];
    const int lrow8 = lane >> 3;
    const int gchunkOff = ((lane & 7) ^ lrow8) * 8;
    const short* gsrc = gbase + (size_t)lrow8 * D_SZ + kbase + gchunkOff;

    const int mo = (wave >> 1) * 64;
    const int no = (wave & 1) * 64;
    const int lr = lane & 15;
    const int lkg = lane >> 4;
    const int x7 = lr & 7;
    const int sl0 = lkg ^ x7;
    const int sl1 = (4 + lkg) ^ x7;
    int aoff[4], boff[4];
#pragma unroll
    for (int f = 0; f < 4; ++f) {
        aoff[f] = (mo + 16 * f + lr) * 64;
        boff[f] = (no + 16 * f + lr) * 64;
    }

    f32x4 acc[4][4] = {};

#pragma unroll
    for (int j = 0; j < 16; ++j)
        gl_lds16(gsrc + (size_t)(8 * j) * D_SZ, lb[0] + j * 512);

    int buf = 0;
    for (int s = 0; s < ksteps; ++s) {
        if (s + 1 < ksteps) {
            short* dst = lb[buf ^ 1];
            const short* g = gsrc + (s + 1) * 64;
#pragma unroll
            for (int j = 0; j < 16; ++j)
                gl_lds16(g + (size_t)(8 * j) * D_SZ, dst + j * 512);
            asm volatile("s_waitcnt vmcnt(16)" ::: "memory");
        } else {
            asm volatile("s_waitcnt vmcnt(0)" ::: "memory");
        }
        fence_barrier();

        __builtin_amdgcn_s_setprio(1);
        {
            const short* pAh = sAh[buf];
            const short* pAl = sAl[buf];
            const short* pBh = sBh[buf];
            const short* pBl = sBl[buf];
#pragma unroll
            for (int ksub = 0; ksub < 2; ++ksub) {
                const int sl = ksub ? sl1 : sl0;
                bf16x8 ah[4], al[4], bh[4], blo[4];
#pragma unroll
                for (int f = 0; f < 4; ++f) {
                    ah[f]  = *(const bf16x8*)&pAh[aoff[f] + sl * 8];
                    al[f]  = *(const bf16x8*)&pAl[aoff[f] + sl * 8];
                }
#pragma unroll
                for (int g = 0; g < 4; ++g) {
                    bh[g]  = *(const bf16x8*)&pBh[boff[g] + sl * 8];
                    blo[g] = *(const bf16x8*)&pBl[boff[g] + sl * 8];
                }
#pragma unroll
                for (int f = 0; f < 4; ++f)
#pragma unroll
                    for (int g = 0; g < 4; ++g)
                        acc[f][g] = MFMA_BF16(ah[f], bh[g], acc[f][g], 0, 0, 0);
#pragma unroll
                for (int f = 0; f < 4; ++f)
#pragma unroll
                    for (int g = 0; g < 4; ++g)
                        acc[f][g] = MFMA_BF16(ah[f], blo[g], acc[f][g], 0, 0, 0);
#pragma unroll
                for (int f = 0; f < 4; ++f)
#pragma unroll
                    for (int g = 0; g < 4; ++g)
                        acc[f][g] = MFMA_BF16(al[f], bh[g], acc[f][g], 0, 0, 0);
            }
        }
        __builtin_amdgcn_s_setprio(0);
        fence_barrier();
        buf ^= 1;
    }

    float* Pout = P + (size_t)ks * (2048u * 512u);
#pragma unroll
    for (int f = 0; f < 4; ++f)
#pragma unroll
        for (int g = 0; g < 4; ++g) {
            const int col  = n0 + no + 16 * g + (lane & 15);
            const int row0 = m0 + mo + 16 * f + (lane >> 4) * 4;
#pragma unroll
            for (int r = 0; r < 4; ++r)
                Pout[(size_t)(row0 + r) * F_SZ + col] = acc[f][g][r];
        }
}

__global__ __launch_bounds__(256) void reduce_feats_split(
    const float* __restrict__ P, float* __restrict__ feats,
    short* __restrict__ Fh, short* __restrict__ Fl,
    const float* __restrict__ W_fc,
    short* __restrict__ Wth, short* __restrict__ Wtl)
{
    const int bid = blockIdx.x;
    const int t = threadIdx.x;
    if (bid < 1024) {
        const int n4 = (2048 * 512) / 4;
        const float* P1 = P + 2048 * 512;
        for (int i4 = bid * 256 + t; i4 < n4; i4 += 1024 * 256) {
            float4 a = ((const float4*)P)[i4];
            float4 b = ((const float4*)P1)[i4];
            float v[4] = {a.x + b.x, a.y + b.y, a.z + b.z, a.w + b.w};
            short4v h, l;
            short hh, ll;
#pragma unroll
            for (int e = 0; e < 4; ++e) {
                feats[i4 * 4 + e] = v[e];
                split_bf16(v[e], hh, ll); h[e] = hh; l[e] = ll;
            }
            ((short4v*)Fh)[i4] = h;
            ((short4v*)Fl)[i4] = l;
        }
    } else {
        __shared__ float tile[64][65];
        const int id = bid - 1024;
        const int k0 = (id & 7) * 64;
        const int c0 = (id >> 3) * 64;
        for (int idx = t; idx < 64 * 64; idx += 256) {
            const int kr = idx >> 6;
            const int cc = idx & 63;
            tile[kr][cc] = (c0 + cc < C_SZ) ? W_fc[(size_t)(k0 + kr) * C_SZ + c0 + cc] : 0.0f;
        }
        __syncthreads();
        const int crow = t >> 2;
#pragma unroll
        for (int cc2 = 0; cc2 < 2; ++cc2) {
            const int ch = (t & 3) * 2 + cc2;
            short8v h, l;
#pragma unroll
            for (int e = 0; e < 8; ++e) {
                short hh, ll;
                split_bf16(tile[ch * 8 + e][crow], hh, ll);
                h[e] = hh; l[e] = ll;
            }
            size_t off = (size_t)(c0 + crow) * F_SZ + k0 + ch * 8;
            *(short8v*)&Wth[off] = h;
            *(short8v*)&Wtl[off] = l;
        }
    }
}

__global__ __launch_bounds__(256) void gemm_fc(
    const short* __restrict__ Ah, const short* __restrict__ Al,
    const short* __restrict__ Bh, const short* __restrict__ Bl,
    const float* __restrict__ bias, float* __restrict__ Cout, int M)
{
    __shared__ __align__(16) short sAh[4096];
    __shared__ __align__(16) short sAl[4096];
    __shared__ __align__(16) short sBh[4096];
    __shared__ __align__(16) short sBl[4096];

    const int t = threadIdx.x;
    const int lane = t & 63;
    const int wave = t >> 6;
    const int n0 = blockIdx.x * 64;
    const int m0 = blockIdx.y * 64;

    const int lrow8 = lane >> 3;
    const int colOff = ((lane & 7) ^ lrow8) * 8;

    short* lbase = (wave == 0) ? sAh : (wave == 1) ? sAl : (wave == 2) ? sBh : sBl;
    const short* gA = (wave == 1) ? Al : Ah;
    const short* gB = (wave == 3) ? Bl : Bh;
    const bool isA = wave < 2;

    const int mo = (wave >> 1) * 32;
    const int no = (wave & 1) * 32;
    const int lr = lane & 15;
    const int lkg = lane >> 4;
    const int x7 = lr & 7;
    const int sl0 = (0 + lkg) ^ x7;
    const int sl1 = (4 + lkg) ^ x7;
    const int ra0 = (mo + lr) * 64,      ra1 = (mo + 16 + lr) * 64;
    const int rb0 = (no + lr) * 64,      rb1 = (no + 16 + lr) * 64;
    const int a00 = ra0 + sl0 * 8, a01 = ra0 + sl1 * 8;
    const int a10 = ra1 + sl0 * 8, a11 = ra1 + sl1 * 8;
    const int b00 = rb0 + sl0 * 8, b01 = rb0 + sl1 * 8;
    const int b10 = rb1 + sl0 * 8, b11 = rb1 + sl1 * 8;

    f32x4 acc[2][2] = {};

    for (int s = 0; s < 8; ++s) {
        __syncthreads();
        if (isA) {
#pragma unroll
            for (int j = 0; j < 8; ++j) {
                int row = m0 + lrow8 + 8 * j;
                if (row > M - 1) row = M - 1;
                gl_lds16(gA + (size_t)row * F_SZ + s * 64 + colOff, lbase + j * 512);
            }
        } else {
#pragma unroll
            for (int j = 0; j < 8; ++j) {
                int row = n0 + lrow8 + 8 * j;
                gl_lds16(gB + (size_t)row * F_SZ + s * 64 + colOff, lbase + j * 512);
            }
        }
        __syncthreads();
        MFMA_BLOCK(a00, a10, b00, b10);
        MFMA_BLOCK(a01, a11, b01, b11);
    }

#pragma unroll
    for (int f = 0; f < 2; ++f)
#pragma unroll
        for (int g = 0; g < 2; ++g) {
            const int col  = n0 + no + g * 16 + (lane & 15);
            if (col >= C_SZ) continue;
            const float bb = bias[col];
            const int row0 = m0 + mo + f * 16 + (lane >> 4) * 4;
#pragma unroll
            for (int r = 0; r < 4; ++r) {
                const int row = row0 + r;
                if (row < M)
                    Cout[(size_t)row * C_SZ + col] = acc[f][g][r] + bb;
            }
        }
}

__global__ __launch_bounds__(64) void argmax_labels(
    const float* __restrict__ logits, const float* __restrict__ partial_Y,
    float* __restrict__ labels_f)
{
    const int i = blockIdx.x;
    const int lane = threadIdx.x;
    float best = -FLT_MAX;
    int bidx = C_SZ;
    for (int c = lane; c < C_SZ; c += 64) {
        if (partial_Y[(size_t)i * C_SZ + c] != 0.0f) {
            float v = logits[(size_t)i * C_SZ + c];
            if (v > best || (v == best && c < bidx)) { best = v; bidx = c; }
        }
    }
#pragma unroll
    for (int off = 32; off; off >>= 1) {
        float ov = __shfl_down(best, off);
        int oi = __shfl_down(bidx, off);
        if (ov > best || (ov == best && oi < bidx)) { best = ov; bidx = oi; }
    }
    if (lane == 0) labels_f[i] = (float)bidx;
}

__global__ __launch_bounds__(512) void proto_update(
    const float* __restrict__ labels_f, const float* __restrict__ feats_q,
    const float* __restrict__ proto, float* __restrict__ new_proto,
    short* __restrict__ NPh, short* __restrict__ NPl)
{
    __shared__ int lab[B_SZ];
    __shared__ float red[8];
    __shared__ float rinv_s;
    const int c = blockIdx.x;
    const int t = threadIdx.x;
    for (int i = t; i < B_SZ; i += 512) lab[i] = (int)labels_f[i];
    __syncthreads();
    float val = proto[(size_t)c * F_SZ + t];
    for (int i = 0; i < B_SZ; ++i) {
        if (lab[i] == c)
            val = PROTO_W * val + (1.0f - PROTO_W) * feats_q[(size_t)i * F_SZ + t];
    }
    float sq = val * val;
#pragma unroll
    for (int off = 32; off; off >>= 1) sq += __shfl_down(sq, off);
    if ((t & 63) == 0) red[t >> 6] = sq;
    __syncthreads();
    if (t == 0) {
        float s = 0.0f;
#pragma unroll
        for (int w = 0; w < 8; ++w) s += red[w];
        rinv_s = 1.0f / sqrtf(s);
    }
    __syncthreads();
    const float v = val * rinv_s;
    new_proto[(size_t)c * F_SZ + t] = v;
    if (NPh) {
        short hh, ll;
        split_bf16(v, hh, ll);
        NPh[(size_t)c * F_SZ + t] = hh;
        NPl[(size_t)c * F_SZ + t] = ll;
    }
}

// ---------------------------------------------------------------------------
extern "C" void kernel_launch(void* const* d_in, const int* in_sizes, int n_in,
                              void* d_out, int out_size, void* d_ws, size_t ws_size,
                              hipStream_t stream)
{
    const float* img_q     = (const float*)d_in[0];
    const float* img_q1    = (const float*)d_in[1];
    const float* partial_Y = (const float*)d_in[2];
    const float* W_enc     = (const float*)d_in[3];
    const float* W_fc      = (const float*)d_in[4];
    const float* b_fc      = (const float*)d_in[5];
    const float* proto     = (const float*)d_in[6];

    float* out       = (float*)d_out;
    float* logits    = out;            // [2048][345]
    float* new_proto = out + 706560;   // [345][512]
    float* scores    = out + 883200;   // [345][345]
    float* labels_f  = out + 1002225;  // [1024]
    float* feats     = out + 1003249;  // [2048][512]

    char* ws = (char*)d_ws;
    short* Xh = (short*)(ws + WS_XH);
    short* Xl = (short*)(ws + WS_XL);
    short* Wh = (short*)(ws + WS_WH);
    short* Wl = (short*)(ws + WS_WL);
    float* P  = (float*)(ws + WS_P);

    if (ws_size >= (size_t)WS2_NEED) {
        short* Wth = (short*)(ws + WS2_WFH);
        short* Wtl = (short*)(ws + WS2_WFL);
        unsigned long long* labPack = (unsigned long long*)(ws + WS2_LAB);

        hipLaunchKernelGGL(convert_pack2, dim3(2096), dim3(256), 0, stream,
                           img_q, img_q1, W_enc, W_fc, Xh, Xl, Wh, Wl, Wth, Wtl,
                           labPack);
        hipLaunchKernelGGL(gemm_ws128_v5, dim3(4, 16, 4), dim3(512), 0, stream,
                           Xh, Xl, Wh, Wl, P);
        hipLaunchKernelGGL(reduce_feats4_f32, dim3(1024), dim3(256), 0, stream,
                           P, feats);
        hipLaunchKernelGGL(fc_logits4, dim3(6, 32), dim3(256), 0, stream,
                           feats, Wth, Wtl, b_fc, partial_Y, logits, labPack);
        hipLaunchKernelGGL(proto_scores_fused, dim3(345), dim3(512), 0, stream,
                           labPack, feats, proto, Wth, Wtl, b_fc,
                           new_proto, scores, labels_f);
    } else {
        short* Fh  = (short*)(ws + WS_FH);
        short* Fl  = (short*)(ws + WS_FL);
        short* Wth = (short*)(ws + WS_WFH);
        short* Wtl = (short*)(ws + WS_WFL);
        short* NPh = (short*)(ws + WS_NPH);
        short* NPl = (short*)(ws + WS_NPL);

        hipLaunchKernelGGL(convert_all, dim3(2048), dim3(256), 0, stream,
                           img_q, img_q1, W_enc, W_fc, Xh, Xl, Wh, Wl,
                           (short*)nullptr, (short*)nullptr,
                           (unsigned long long*)nullptr);
        hipLaunchKernelGGL(gemm_ws128, dim3(4, 16, 2), dim3(256), 0, stream,
                           Xh, Xl, Wh, Wl, P, 64);
        hipLaunchKernelGGL(reduce_feats_split, dim3(1072), dim3(256), 0, stream,
                           P, feats, Fh, Fl, W_fc, Wth, Wtl);
        hipLaunchKernelGGL(gemm_fc, dim3(6, 32), dim3(256), 0, stream,
                           Fh, Fl, Wth, Wtl, b_fc, logits, 2048);
        hipLaunchKernelGGL(argmax_labels, dim3(1024), dim3(64), 0, stream,
                           logits, partial_Y, labels_f);
        hipLaunchKernelGGL(proto_update, dim3(345), dim3(512), 0, stream,
                           labels_f, feats, proto, new_proto, NPh, NPl);
        hipLaunchKernelGGL(gemm_fc, dim3(6, 6), dim3(256), 0, stream,
                           NPh, NPl, Wth, Wtl, b_fc, scores, C_SZ);
    }
}